// Round 8
// baseline (315.547 us; speedup 1.0000x reference)
//
#include <hip/hip_runtime.h>
#include <math.h>

#define N_NODES 50000
#define N_PAD   50048          // padded to multiple of 128 for GEMM tiles
#define N_EDGES 800000
#define CSR_CAP 1200000        // >= sum pad8(deg) <= 800000 + 50000*7
#define IN_F 128
#define H_F 256
#define OUT_F 10
#define N_G 128
#define NCHUNKS 196            // ceil(N_NODES/256)

// partitioned-histogram geometry (atomic-free CSR build)
#define P_PART 16
#define R_RANGE 16
#define PE (N_EDGES / P_PART)      // 50000 edges / partition
#define RN (N_NODES / R_RANGE)     // 3125 nodes / range

typedef __attribute__((ext_vector_type(4))) float f32x4;
typedef __attribute__((ext_vector_type(2))) float f32x2;
typedef unsigned char u8;

// ---- fp8 e4m3 (OCP) helpers: HW packed converts (imm word-select) ----
__device__ inline f32x2 fp8x2_f32_lo(unsigned int v) {
    return __builtin_amdgcn_cvt_pk_f32_fp8(v, false);
}
__device__ inline f32x2 fp8x2_f32_hi(unsigned int v) {
    return __builtin_amdgcn_cvt_pk_f32_fp8(v, true);
}
__device__ inline unsigned int f32_fp8x2_lo(float a, float b, unsigned int old) {
    return __builtin_amdgcn_cvt_pk_fp8_f32(a, b, old, false);
}
__device__ inline unsigned int f32_fp8x2_hi(float a, float b, unsigned int old) {
    return __builtin_amdgcn_cvt_pk_fp8_f32(a, b, old, true);
}
__device__ inline u8 f32_fp8(float a) {
    return (u8)(f32_fp8x2_lo(a, a, 0u) & 0xff);
}
// ---- bf16 helpers (packed CSR weight) ----
__device__ inline ushort f2bf(float x) {
    union { float f; unsigned int u; } v; v.f = x;
    unsigned int r = v.u + 0x7fff + ((v.u >> 16) & 1);
    return (ushort)(r >> 16);
}
__device__ inline float bf2f(ushort u) {
    union { unsigned int u; float f; } v; v.u = ((unsigned int)u) << 16; return v.f;
}

// async global->LDS, 16 B per lane; lds dest = wave-uniform base + lane*16
__device__ inline void gl2lds16(const void* g, void* l) {
    __builtin_amdgcn_global_load_lds(
        (const __attribute__((address_space(1))) unsigned int*)g,
        (__attribute__((address_space(3))) unsigned int*)l,
        16, 0, 0);
}

// ------------------------------------------------------------------
// Fused prep: partitioned LDS histogram (NO global atomics; rank =
// LDS-local rank within (partition,node)) + fp8 converts + graph
// starts. Histo cell (p,r): LDS-count partition p's edges landing in
// node range r; write H[p][*] slice + per-edge local rank. lambda~1
// per LDS counter -> near-zero contention. 12.5KB LDS/block keeps
// occupancy high; hides under the BW-bound converts.
// ------------------------------------------------------------------
#define PREP_HB  (P_PART * R_RANGE)      // 256 histo blocks
#define PREP_X   (PREP_HB + 6250)
#define PREP_T0  (PREP_X + 128)
#define PREP_T1  (PREP_T0 + 256)
#define PREP_T2  (PREP_T1 + 256)
#define PREP_GS  (PREP_T2 + NCHUNKS)

__global__ __launch_bounds__(256) void prep_kernel(
    const int* __restrict__ col, int* __restrict__ H,
    int* __restrict__ rank,
    const float* __restrict__ x, u8* __restrict__ xb,
    const float* __restrict__ W0, u8* __restrict__ W0t,
    const float* __restrict__ W1, u8* __restrict__ W1t,
    const float* __restrict__ W2, u8* __restrict__ W2t,
    const int* __restrict__ batch, int* __restrict__ gstart) {
    __shared__ int hcnt[RN];
    int b = blockIdx.x;
    int tid = threadIdx.x;
    if (b < PREP_HB) {
        int p = b & (P_PART - 1);
        int r = b >> 4;
        for (int j = tid; j < RN; j += 256) hcnt[j] = 0;
        __syncthreads();
        int nb = r * RN;
        int e0 = p * PE;
        for (int e = e0 + tid; e < e0 + PE; e += 256) {
            int c = col[e];
            unsigned int d = (unsigned int)(c - nb);
            if (d < RN) {
                int lr = atomicAdd(&hcnt[d], 1);   // LDS atomic: cheap
                rank[e] = lr;
            }
        }
        __syncthreads();
        for (int j = tid; j < RN; j += 256) H[p * N_NODES + nb + j] = hcnt[j];
    } else if (b < PREP_X) {
        int i = (b - PREP_HB) * 256 + tid;      // < 1,600,000 exactly
        float4 v = *(const float4*)(x + (size_t)i * 4);
        unsigned int p = f32_fp8x2_lo(v.x, v.y, 0u);
        p = f32_fp8x2_hi(v.z, v.w, p);
        *(unsigned int*)(xb + (size_t)i * 4) = p;
    } else if (b < PREP_T0) {
        int idx = (b - PREP_X) * 256 + tid;     // < 32768
        int k = idx >> 8, nn = idx & 255;       // K=128, Nc=256
        W0t[nn * IN_F + k] = f32_fp8(W0[idx]);
    } else if (b < PREP_T1) {
        int idx = (b - PREP_T0) * 256 + tid;    // < 65536
        int k = idx >> 8, nn = idx & 255;
        W1t[nn * H_F + k] = f32_fp8(W1[idx]);
    } else if (b < PREP_T2) {
        int idx = (b - PREP_T1) * 256 + tid;
        int k = idx >> 8, nn = idx & 255;
        W2t[nn * H_F + k] = f32_fp8(W2[idx]);
    } else {
        int i = (b - PREP_T2) * 256 + tid;
        if (i >= N_NODES) return;
        int bb = batch[i];
        if (i == 0) {
            for (int g = 0; g <= bb; ++g) gstart[g] = 0;
        } else {
            int p = batch[i - 1];
            if (p != bb) { for (int g = p + 1; g <= bb; ++g) gstart[g] = i; }
        }
        if (i == N_NODES - 1) {
            for (int g = bb + 1; g <= N_G; ++g) gstart[g] = N_NODES;
        }
    }
}

// ------------------------------------------------------------------
// chunk_reduce: counts[i] = sum_p H[p][i] (coalesced per p-slice),
// then per-chunk sums of PADDED counts. Replaces the counts memset.
// ------------------------------------------------------------------
__global__ __launch_bounds__(256) void chunk_reduce(const int* __restrict__ H,
                                                    int* __restrict__ counts,
                                                    int* __restrict__ csum, int n) {
    int i = blockIdx.x * 256 + threadIdx.x;
    int total = 0;
    if (i < n) {
        #pragma unroll
        for (int p = 0; p < P_PART; ++p) total += H[p * N_NODES + i];
        counts[i] = total;
    }
    int v = (i < n) ? ((total + 7) & ~7) : 0;
    #pragma unroll
    for (int off = 32; off; off >>= 1) v += __shfl_down(v, off);
    __shared__ int ws[4];
    if ((threadIdx.x & 63) == 0) ws[threadIdx.x >> 6] = v;
    __syncthreads();
    if (threadIdx.x == 0) csum[blockIdx.x] = ws[0] + ws[1] + ws[2] + ws[3];
}

// ------------------------------------------------------------------
// scan (over padded counts, csum-based block base) + dinv + zero
// padding CSR slots + in-place exclusive-prefix of H across p
// (H[p][i] becomes base of partition p within node i's segment).
// ------------------------------------------------------------------
__global__ __launch_bounds__(256) void scan_dinv_kernel(const int* __restrict__ counts,
                                                        const int* __restrict__ csum,
                                                        int* __restrict__ offsets,
                                                        int* __restrict__ H,
                                                        float* __restrict__ dinv,
                                                        unsigned int* __restrict__ csr_ew,
                                                        int n) {
    int tid = threadIdx.x;
    int lane = tid & 63, wid = tid >> 6;
    int cv = (tid < NCHUNKS) ? csum[tid] : 0;
    int xc = cv;
    #pragma unroll
    for (int off = 1; off < 64; off <<= 1) {
        int t = __shfl_up(xc, off);
        if (lane >= off) xc += t;
    }
    __shared__ int cw[4], cpre[4];
    __shared__ int cexcl[257];
    if (lane == 63) cw[wid] = xc;
    __syncthreads();
    if (tid == 0) { int s = 0; for (int k = 0; k < 4; ++k) { cpre[k] = s; s += cw[k]; } }
    __syncthreads();
    cexcl[tid] = cpre[wid] + xc - cv;
    if (tid == 255) cexcl[256] = cpre[3] + cw[3];
    __syncthreads();
    int base = cexcl[blockIdx.x];
    int i = blockIdx.x * 256 + tid;
    int v = (i < n) ? counts[i] : 0;
    int pv = (v + 7) & ~7;
    int x = pv;
    #pragma unroll
    for (int off = 1; off < 64; off <<= 1) {
        int t = __shfl_up(x, off);
        if (lane >= off) x += t;
    }
    __shared__ int wsum[4], wpre[4];
    if (lane == 63) wsum[wid] = x;
    __syncthreads();
    if (tid == 0) { int s = 0; for (int k = 0; k < 4; ++k) { wpre[k] = s; s += wsum[k]; } }
    __syncthreads();
    if (i < n) {
        int o = base + wpre[wid] + x - pv;       // exclusive, padded
        offsets[i] = o;
        dinv[i] = rsqrtf((float)(v + 1));
        for (int z = v; z < pv; ++z) csr_ew[o + z] = 0u;   // zero padding slots
        // exclusive-prefix H across partitions (in place, coalesced per slice)
        int s = 0;
        #pragma unroll
        for (int p = 0; p < P_PART; ++p) {
            int hv = H[p * N_NODES + i];
            H[p * N_NODES + i] = s;
            s += hv;
        }
    }
    if (blockIdx.x == 0 && tid == 0) offsets[n] = cexcl[NCHUNKS];
}

// Packed CSR: entry = src (16 bits) | bf16 weight << 16; slot =
// offsets[c] + Hexcl[p][c] + rank[e] (fully atomic-free).
// 2 independent edges/thread for ILP.
__global__ __launch_bounds__(256) void fill_csr_kernel(const int* __restrict__ row,
                                                       const int* __restrict__ col,
                                                       const int* __restrict__ offsets,
                                                       const int* __restrict__ H,
                                                       const int* __restrict__ rank,
                                                       const float* __restrict__ dinv,
                                                       unsigned int* __restrict__ csr_ew) {
    int e0 = blockIdx.x * 512 + threadIdx.x;
    int e1 = e0 + 256;
    int c0 = -1, c1 = -1, r0 = 0, r1 = 0, k0 = 0, k1 = 0;
    if (e0 < N_EDGES) { c0 = col[e0]; r0 = row[e0]; k0 = rank[e0]; }
    if (e1 < N_EDGES) { c1 = col[e1]; r1 = row[e1]; k1 = rank[e1]; }
    float dc0 = 0.f, dr0 = 0.f, dc1 = 0.f, dr1 = 0.f;
    int h0 = 0, h1 = 0;
    if (c0 >= 0) {
        dc0 = dinv[c0]; dr0 = dinv[r0];
        h0 = H[(e0 / PE) * N_NODES + c0];
    }
    if (c1 >= 0) {
        dc1 = dinv[c1]; dr1 = dinv[r1];
        h1 = H[(e1 / PE) * N_NODES + c1];
    }
    if (c0 >= 0)
        csr_ew[offsets[c0] + h0 + k0] = (unsigned int)r0 | ((unsigned int)f2bf(dc0 * dr0) << 16);
    if (c1 >= 0)
        csr_ew[offsets[c1] + h1 + k1] = (unsigned int)r1 | ((unsigned int)f2bf(dc1 * dr1) << 16);
}

// ------------------------------------------------------------------
// fp8 MFMA GEMM: C[N_PAD x 256] = A[N_PAD x K] @ Bt^T   (Bt is [256][K], fp8)
// 128x128 tile / block (4 waves 2x2), BK=128, async global_load_lds staging.
// ------------------------------------------------------------------
template <int K, bool RELU>
__global__ __launch_bounds__(256) void gemm_fp8(const u8* __restrict__ A,
                                                const u8* __restrict__ Bt,
                                                u8* __restrict__ C) {
    __shared__ u8 As[4 * 4096];
    __shared__ u8 Bs[4 * 4096];
    int tid = threadIdx.x;
    int lane = tid & 63;
    int w = tid >> 6;
    int wm = w & 1, wn = w >> 1;
    int l16 = lane & 15, quad = lane >> 4;
    int row0 = blockIdx.x * 128;
    int col0 = blockIdx.y * 128;
    f32x4 acc[4][4] = {};

    int sr = tid >> 1;             // staging row 0..127
    int sh = (tid & 1) * 16;       // half-plane-row byte offset
    const u8* ga = A + (size_t)(row0 + sr) * K + sh;
    const u8* gb = Bt + (size_t)(col0 + sr) * K + sh;

    #pragma unroll
    for (int k0 = 0; k0 < K; k0 += 128) {
        if (k0) __syncthreads();
        #pragma unroll
        for (int q = 0; q < 4; ++q) {   // k-plane within stage
            gl2lds16(ga + k0 + q * 32, As + q * 4096 + w * 1024);
            gl2lds16(gb + k0 + q * 32, Bs + q * 4096 + w * 1024);
        }
        __syncthreads();
        #pragma unroll
        for (int h = 0; h < 4; ++h) {
            long af[4], bfr[4];
            #pragma unroll
            for (int i = 0; i < 4; ++i)
                af[i] = *(const long*)&As[h * 4096 + (wm * 64 + i * 16 + l16) * 32 + quad * 8];
            #pragma unroll
            for (int j = 0; j < 4; ++j)
                bfr[j] = *(const long*)&Bs[h * 4096 + (wn * 64 + j * 16 + l16) * 32 + quad * 8];
            #pragma unroll
            for (int i = 0; i < 4; ++i)
                #pragma unroll
                for (int j = 0; j < 4; ++j)
                    acc[i][j] = __builtin_amdgcn_mfma_f32_16x16x32_fp8_fp8(af[i], bfr[j], acc[i][j], 0, 0, 0);
        }
    }
    // epilogue: C/D layout col=lane&15, row=quad*4+reg (dtype-independent)
    #pragma unroll
    for (int i = 0; i < 4; ++i) {
        int rowb = row0 + wm * 64 + i * 16 + quad * 4;
        #pragma unroll
        for (int r = 0; r < 4; ++r) {
            int grow = rowb + r;
            #pragma unroll
            for (int j = 0; j < 4; ++j) {
                int gcol = col0 + wn * 64 + j * 16 + l16;
                float v = acc[i][j][r];
                if (RELU) v = fmaxf(v, 0.f);
                C[(size_t)grow * H_F + gcol] = f32_fp8(v);
            }
        }
    }
}

// ------------------------------------------------------------------
// GCN aggregation, 128-ch fp8 (layer-0, pre-GEMM), NO relu.
// ------------------------------------------------------------------
__global__ __launch_bounds__(256) void aggregate128(const u8* __restrict__ hw,
                                                    const float* __restrict__ dinv,
                                                    const int* __restrict__ offsets,
                                                    const unsigned int* __restrict__ csr_ew,
                                                    u8* __restrict__ hout) {
    int w = threadIdx.x >> 6;
    int lane = threadIdx.x & 63;
    int i = blockIdx.x * 4 + w;
    if (i >= N_NODES) return;
    float di = dinv[i];
    const u8* base = hw + (size_t)lane * 2;
    unsigned int su = *(const unsigned short*)(base + (size_t)i * IN_F);
    f32x2 sv = fp8x2_f32_lo(su);
    float s = di * di;
    float a0 = s * sv.x, a1 = s * sv.y;
    int t = __builtin_amdgcn_readfirstlane(offsets[i]);
    int end = __builtin_amdgcn_readfirstlane(offsets[i + 1]);
    if (t < end) {
        uint4 eA = *(const uint4*)(csr_ew + t);
        uint4 eB = *(const uint4*)(csr_ew + t + 4);
        for (; t < end; t += 8) {
            uint4 nA, nB;
            if (t + 8 < end) {
                nA = *(const uint4*)(csr_ew + t + 8);
                nB = *(const uint4*)(csr_ew + t + 12);
            }
            unsigned int e[8] = {eA.x, eA.y, eA.z, eA.w, eB.x, eB.y, eB.z, eB.w};
            unsigned int v[8];
            #pragma unroll
            for (int u = 0; u < 8; ++u)
                v[u] = *(const unsigned short*)(base + (size_t)(e[u] & 0xffff) * IN_F);
            #pragma unroll
            for (int u = 0; u < 8; ++u) {
                float wq = bf2f((ushort)(e[u] >> 16));
                f32x2 f = fp8x2_f32_lo(v[u]);
                a0 += wq * f.x; a1 += wq * f.y;
            }
            eA = nA; eB = nB;
        }
    }
    unsigned int o = f32_fp8x2_lo(a0, a1, 0u);
    *(unsigned short*)(hout + (size_t)i * IN_F + lane * 2) = (unsigned short)(o & 0xffff);
}

// ------------------------------------------------------------------
// GCN aggregation, 256-ch fp8, + relu. Padded, pipelined, scalar descr.
// ------------------------------------------------------------------
__global__ __launch_bounds__(256) void aggregate256(const u8* __restrict__ hw,
                                                    const float* __restrict__ dinv,
                                                    const int* __restrict__ offsets,
                                                    const unsigned int* __restrict__ csr_ew,
                                                    u8* __restrict__ hout) {
    int w = threadIdx.x >> 6;
    int lane = threadIdx.x & 63;
    int i = blockIdx.x * 4 + w;
    if (i >= N_NODES) return;
    float di = dinv[i];
    const u8* base = hw + (size_t)lane * 4;
    unsigned int su = *(const unsigned int*)(base + (size_t)i * H_F);
    f32x2 slo = fp8x2_f32_lo(su), shi = fp8x2_f32_hi(su);
    float s = di * di;
    float a0 = s * slo.x, a1 = s * slo.y, a2 = s * shi.x, a3 = s * shi.y;
    int t = __builtin_amdgcn_readfirstlane(offsets[i]);
    int end = __builtin_amdgcn_readfirstlane(offsets[i + 1]);
    if (t < end) {
        uint4 eA = *(const uint4*)(csr_ew + t);
        uint4 eB = *(const uint4*)(csr_ew + t + 4);
        for (; t < end; t += 8) {
            uint4 nA, nB;
            if (t + 8 < end) {
                nA = *(const uint4*)(csr_ew + t + 8);
                nB = *(const uint4*)(csr_ew + t + 12);
            }
            unsigned int e[8] = {eA.x, eA.y, eA.z, eA.w, eB.x, eB.y, eB.z, eB.w};
            unsigned int v[8];
            #pragma unroll
            for (int u = 0; u < 8; ++u)
                v[u] = *(const unsigned int*)(base + (size_t)(e[u] & 0xffff) * H_F);
            #pragma unroll
            for (int u = 0; u < 8; ++u) {
                float wq = bf2f((ushort)(e[u] >> 16));
                f32x2 lo = fp8x2_f32_lo(v[u]), hi = fp8x2_f32_hi(v[u]);
                a0 += wq * lo.x; a1 += wq * lo.y;
                a2 += wq * hi.x; a3 += wq * hi.y;
            }
            eA = nA; eB = nB;
        }
    }
    unsigned int o = f32_fp8x2_lo(fmaxf(a0, 0.f), fmaxf(a1, 0.f), 0u);
    o = f32_fp8x2_hi(fmaxf(a2, 0.f), fmaxf(a3, 0.f), o);
    *(unsigned int*)(hout + (size_t)i * H_F + lane * 4) = o;
}

// ------------------------------------------------------------------
// Fused pool + MLP head: one 1024-thread block (16 waves) per graph.
// ------------------------------------------------------------------
__global__ __launch_bounds__(1024) void pool_mlp_kernel(const u8* __restrict__ h,
                                                        const int* __restrict__ gstart,
                                                        const float* __restrict__ Wm1,
                                                        const float* __restrict__ bm1,
                                                        const float* __restrict__ Wm2,
                                                        const float* __restrict__ bm2,
                                                        float* __restrict__ out) {
    __shared__ float sm[16][H_F];
    __shared__ float p[H_F];
    __shared__ float hmid[H_F];
    __shared__ float lastv[OUT_F];
    __shared__ float stats[2];
    int g = blockIdx.x;
    int s = gstart[g], e = gstart[g + 1];
    int w = threadIdx.x >> 6;        // 0..15
    int lane = threadIdx.x & 63;
    float a0 = 0.f, a1 = 0.f, a2 = 0.f, a3 = 0.f;
    for (int i = s + w; i < e; i += 16) {
        unsigned int v = *(const unsigned int*)(h + (size_t)i * H_F + lane * 4);
        f32x2 lo = fp8x2_f32_lo(v), hi = fp8x2_f32_hi(v);
        a0 += lo.x; a1 += lo.y; a2 += hi.x; a3 += hi.y;
    }
    *(f32x4*)&sm[w][lane * 4] = (f32x4){a0, a1, a2, a3};
    __syncthreads();
    int j = threadIdx.x;
    int cnt = e - s;
    if (j < H_F) {
        float t = 0.f;
        #pragma unroll
        for (int k = 0; k < 16; ++k) t += sm[k][j];
        p[j] = t / (float)max(cnt, 1);
    }
    __syncthreads();
    if (j < H_F) {
        float acc = bm1[j];
        for (int k = 0; k < H_F; ++k) acc += p[k] * Wm1[k * H_F + j];
        hmid[j] = fmaxf(acc, 0.f);
    }
    __syncthreads();
    if (j < OUT_F) {
        float a = bm2[j];
        for (int k = 0; k < H_F; ++k) a += hmid[k] * Wm2[k * OUT_F + j];
        lastv[j] = a;
    }
    __syncthreads();
    if (j == 0) {
        float m = -1e30f;
        for (int o = 0; o < OUT_F; ++o) m = fmaxf(m, lastv[o]);
        float sxp = 0.f;
        for (int o = 0; o < OUT_F; ++o) sxp += expf(lastv[o] - m);
        stats[0] = m; stats[1] = logf(sxp);
    }
    __syncthreads();
    if (j < OUT_F) {
        float v = lastv[j];
        out[g * OUT_F + j] = v - stats[0] - stats[1];
        out[(size_t)N_G * OUT_F + g * OUT_F + j] = 1.f / (1.f + expf(-v));
        out[(size_t)2 * N_G * OUT_F + g * OUT_F + j] = v;
    }
}

// ------------------------------------------------------------------
extern "C" void kernel_launch(void* const* d_in, const int* in_sizes, int n_in,
                              void* d_out, int out_size, void* d_ws, size_t ws_size,
                              hipStream_t stream) {
    const float* x   = (const float*)d_in[0];
    const int* edge_index = (const int*)d_in[1];
    const int* batch = (const int*)d_in[3];
    const float* W0  = (const float*)d_in[4];
    const float* W1  = (const float*)d_in[5];
    const float* W2  = (const float*)d_in[6];
    const float* Wm1 = (const float*)d_in[7];
    const float* bm1 = (const float*)d_in[8];
    const float* Wm2 = (const float*)d_in[9];
    const float* bm2 = (const float*)d_in[10];
    float* out = (float*)d_out;

    char* ws = (char*)d_ws;
    size_t off = 0;
    auto alloc = [&](size_t bytes) -> void* {
        void* p = ws + off; off += (bytes + 255) & ~(size_t)255; return p;
    };
    u8* xb       = (u8*)alloc((size_t)N_PAD * IN_F);
    u8* bufA     = (u8*)alloc((size_t)N_PAD * H_F);
    u8* bufB     = (u8*)alloc((size_t)N_PAD * H_F);
    u8* t0       = (u8*)alloc((size_t)N_PAD * IN_F);
    u8* W0t      = (u8*)alloc((size_t)H_F * IN_F);
    u8* W1t      = (u8*)alloc((size_t)H_F * H_F);
    u8* W2t      = (u8*)alloc((size_t)H_F * H_F);
    float* dinv    = (float*)alloc((size_t)N_NODES * 4);
    int*   counts  = (int*)alloc((size_t)N_NODES * 4);
    int*   offsets = (int*)alloc((size_t)(N_NODES + 1) * 4);
    int*   rank    = (int*)alloc((size_t)N_EDGES * 4);
    int*   H       = (int*)alloc((size_t)P_PART * N_NODES * 4);
    unsigned int* csr_ew = (unsigned int*)alloc((size_t)CSR_CAP * 4);
    int*   csum    = (int*)alloc((size_t)256 * 4);
    int*   gstart  = (int*)alloc((size_t)(N_G + 1) * 4);

    const int* row = edge_index;
    const int* col = edge_index + N_EDGES;

    prep_kernel<<<PREP_GS, 256, 0, stream>>>(col, H, rank, x, xb, W0, W0t,
                                             W1, W1t, W2, W2t, batch, gstart);
    chunk_reduce<<<NCHUNKS, 256, 0, stream>>>(H, counts, csum, N_NODES);
    scan_dinv_kernel<<<NCHUNKS, 256, 0, stream>>>(counts, csum, offsets, H, dinv,
                                                  csr_ew, N_NODES);
    fill_csr_kernel<<<1563, 256, 0, stream>>>(row, col, offsets, H, rank, dinv, csr_ew);

    dim3 gg(N_PAD / 128, H_F / 128);
    int agg_blocks = (N_NODES + 3) / 4;
    // layer 0: aggregate-first (linear ops commute), relu in GEMM epilogue
    aggregate128<<<agg_blocks, 256, 0, stream>>>(xb, dinv, offsets, csr_ew, t0);
    gemm_fp8<IN_F, true><<<gg, 256, 0, stream>>>(t0, W0t, bufA);
    // layer 1
    gemm_fp8<H_F, false><<<gg, 256, 0, stream>>>(bufA, W1t, bufB);
    aggregate256<<<agg_blocks, 256, 0, stream>>>(bufB, dinv, offsets, csr_ew, bufA);
    // layer 2
    gemm_fp8<H_F, false><<<gg, 256, 0, stream>>>(bufA, W2t, bufB);
    aggregate256<<<agg_blocks, 256, 0, stream>>>(bufB, dinv, offsets, csr_ew, bufA);

    pool_mlp_kernel<<<N_G, 1024, 0, stream>>>(bufA, gstart, Wm1, bm1, Wm2, bm2, out);
}

// Round 9
// 290.983 us; speedup vs baseline: 1.0844x; 1.0844x over previous
//
#include <hip/hip_runtime.h>
#include <math.h>

#define N_NODES 50000
#define N_PAD   50048          // padded to multiple of 128 for GEMM tiles
#define N_EDGES 800000
#define CSR_CAP 1200000        // >= sum pad8(deg) <= 800000 + 50000*7
#define IN_F 128
#define H_F 256
#define OUT_F 10
#define N_G 128
#define NCHUNKS 196            // ceil(N_NODES/256)
#define NCOPY 4                // count-array copies (atomic chain depth 16->4)

typedef __attribute__((ext_vector_type(4))) float f32x4;
typedef __attribute__((ext_vector_type(2))) float f32x2;
typedef unsigned char u8;

// ---- fp8 e4m3 (OCP) helpers: HW packed converts (imm word-select) ----
__device__ inline f32x2 fp8x2_f32_lo(unsigned int v) {
    return __builtin_amdgcn_cvt_pk_f32_fp8(v, false);
}
__device__ inline f32x2 fp8x2_f32_hi(unsigned int v) {
    return __builtin_amdgcn_cvt_pk_f32_fp8(v, true);
}
__device__ inline unsigned int f32_fp8x2_lo(float a, float b, unsigned int old) {
    return __builtin_amdgcn_cvt_pk_fp8_f32(a, b, old, false);
}
__device__ inline unsigned int f32_fp8x2_hi(float a, float b, unsigned int old) {
    return __builtin_amdgcn_cvt_pk_fp8_f32(a, b, old, true);
}
__device__ inline u8 f32_fp8(float a) {
    return (u8)(f32_fp8x2_lo(a, a, 0u) & 0xff);
}
// ---- bf16 helpers (packed CSR weight) ----
__device__ inline ushort f2bf(float x) {
    union { float f; unsigned int u; } v; v.f = x;
    unsigned int r = v.u + 0x7fff + ((v.u >> 16) & 1);
    return (ushort)(r >> 16);
}
__device__ inline float bf2f(ushort u) {
    union { unsigned int u; float f; } v; v.u = ((unsigned int)u) << 16; return v.f;
}

// async global->LDS, 16 B per lane; lds dest = wave-uniform base + lane*16
__device__ inline void gl2lds16(const void* g, void* l) {
    __builtin_amdgcn_global_load_lds(
        (const __attribute__((address_space(1))) unsigned int*)g,
        (__attribute__((address_space(3))) unsigned int*)l,
        16, 0, 0);
}

// ------------------------------------------------------------------
// Fused prep: edge-dst histogram (atomic return = per-edge rank,
// spread over NCOPY=4 count arrays keyed by e&3 to cut same-address
// serialization depth 16->4) + fp8 converts + graph starts.
// ------------------------------------------------------------------
#define PREP_HIST 782
#define PREP_X   (PREP_HIST + 6250)
#define PREP_T0  (PREP_X + 128)
#define PREP_T1  (PREP_T0 + 256)
#define PREP_T2  (PREP_T1 + 256)
#define PREP_GS  (PREP_T2 + NCHUNKS)

__global__ __launch_bounds__(256) void prep_kernel(
    const int* __restrict__ col, int* __restrict__ counts4,
    int* __restrict__ rank,
    const float* __restrict__ x, u8* __restrict__ xb,
    const float* __restrict__ W0, u8* __restrict__ W0t,
    const float* __restrict__ W1, u8* __restrict__ W1t,
    const float* __restrict__ W2, u8* __restrict__ W2t,
    const int* __restrict__ batch, int* __restrict__ gstart) {
    int b = blockIdx.x;
    int tid = threadIdx.x;
    if (b < PREP_HIST) {
        int base = b * 1024 + tid;
        // e = base + u*256; e&3 == base&3 for all u (256 % 4 == 0)
        int* cb = counts4 + (size_t)(base & 3) * N_NODES;
        int c[4];
        #pragma unroll
        for (int u = 0; u < 4; ++u) {
            int e = base + u * 256;
            c[u] = (e < N_EDGES) ? col[e] : -1;
        }
        int rk[4];
        #pragma unroll
        for (int u = 0; u < 4; ++u)
            if (c[u] >= 0) rk[u] = atomicAdd(&cb[c[u]], 1);
        #pragma unroll
        for (int u = 0; u < 4; ++u)
            if (c[u] >= 0) rank[base + u * 256] = rk[u];
    } else if (b < PREP_X) {
        int i = (b - PREP_HIST) * 256 + tid;    // < 1,600,000 exactly
        float4 v = *(const float4*)(x + (size_t)i * 4);
        unsigned int p = f32_fp8x2_lo(v.x, v.y, 0u);
        p = f32_fp8x2_hi(v.z, v.w, p);
        *(unsigned int*)(xb + (size_t)i * 4) = p;
    } else if (b < PREP_T0) {
        int idx = (b - PREP_X) * 256 + tid;     // < 32768
        int k = idx >> 8, nn = idx & 255;       // K=128, Nc=256
        W0t[nn * IN_F + k] = f32_fp8(W0[idx]);
    } else if (b < PREP_T1) {
        int idx = (b - PREP_T0) * 256 + tid;    // < 65536
        int k = idx >> 8, nn = idx & 255;
        W1t[nn * H_F + k] = f32_fp8(W1[idx]);
    } else if (b < PREP_T2) {
        int idx = (b - PREP_T1) * 256 + tid;
        int k = idx >> 8, nn = idx & 255;
        W2t[nn * H_F + k] = f32_fp8(W2[idx]);
    } else {
        int i = (b - PREP_T2) * 256 + tid;
        if (i >= N_NODES) return;
        int bb = batch[i];
        if (i == 0) {
            for (int g = 0; g <= bb; ++g) gstart[g] = 0;
        } else {
            int p = batch[i - 1];
            if (p != bb) { for (int g = p + 1; g <= bb; ++g) gstart[g] = i; }
        }
        if (i == N_NODES - 1) {
            for (int g = bb + 1; g <= N_G; ++g) gstart[g] = N_NODES;
        }
    }
}

// ------------------------------------------------------------------
// chunk_reduce: counts[i] = sum_k counts4[k][i] (coalesced slices),
// then per-chunk sums of PADDED counts.
// ------------------------------------------------------------------
__global__ __launch_bounds__(256) void chunk_reduce(const int* __restrict__ counts4,
                                                    int* __restrict__ counts,
                                                    int* __restrict__ csum, int n) {
    int i = blockIdx.x * 256 + threadIdx.x;
    int total = 0;
    if (i < n) {
        #pragma unroll
        for (int k = 0; k < NCOPY; ++k) total += counts4[(size_t)k * N_NODES + i];
        counts[i] = total;
    }
    int v = (i < n) ? ((total + 7) & ~7) : 0;
    #pragma unroll
    for (int off = 32; off; off >>= 1) v += __shfl_down(v, off);
    __shared__ int ws[4];
    if ((threadIdx.x & 63) == 0) ws[threadIdx.x >> 6] = v;
    __syncthreads();
    if (threadIdx.x == 0) csum[blockIdx.x] = ws[0] + ws[1] + ws[2] + ws[3];
}

// ------------------------------------------------------------------
// scan (over padded counts, csum-based block base) + dinv + zero
// padding CSR slots + in-place exclusive-prefix of counts4 across k
// (counts4[k][i] becomes base of copy k within node i's segment).
// ------------------------------------------------------------------
__global__ __launch_bounds__(256) void scan_dinv_kernel(const int* __restrict__ counts,
                                                        const int* __restrict__ csum,
                                                        int* __restrict__ offsets,
                                                        int* __restrict__ counts4,
                                                        float* __restrict__ dinv,
                                                        unsigned int* __restrict__ csr_ew,
                                                        int n) {
    int tid = threadIdx.x;
    int lane = tid & 63, wid = tid >> 6;
    int cv = (tid < NCHUNKS) ? csum[tid] : 0;
    int xc = cv;
    #pragma unroll
    for (int off = 1; off < 64; off <<= 1) {
        int t = __shfl_up(xc, off);
        if (lane >= off) xc += t;
    }
    __shared__ int cw[4], cpre[4];
    __shared__ int cexcl[257];
    if (lane == 63) cw[wid] = xc;
    __syncthreads();
    if (tid == 0) { int s = 0; for (int k = 0; k < 4; ++k) { cpre[k] = s; s += cw[k]; } }
    __syncthreads();
    cexcl[tid] = cpre[wid] + xc - cv;
    if (tid == 255) cexcl[256] = cpre[3] + cw[3];
    __syncthreads();
    int base = cexcl[blockIdx.x];
    int i = blockIdx.x * 256 + tid;
    int v = (i < n) ? counts[i] : 0;
    int pv = (v + 7) & ~7;
    int x = pv;
    #pragma unroll
    for (int off = 1; off < 64; off <<= 1) {
        int t = __shfl_up(x, off);
        if (lane >= off) x += t;
    }
    __shared__ int wsum[4], wpre[4];
    if (lane == 63) wsum[wid] = x;
    __syncthreads();
    if (tid == 0) { int s = 0; for (int k = 0; k < 4; ++k) { wpre[k] = s; s += wsum[k]; } }
    __syncthreads();
    if (i < n) {
        int o = base + wpre[wid] + x - pv;       // exclusive, padded
        offsets[i] = o;
        dinv[i] = rsqrtf((float)(v + 1));
        for (int z = v; z < pv; ++z) csr_ew[o + z] = 0u;   // zero padding slots
        // exclusive-prefix across the 4 copies (in place, coalesced slices)
        int s = 0;
        #pragma unroll
        for (int k = 0; k < NCOPY; ++k) {
            int hv = counts4[(size_t)k * N_NODES + i];
            counts4[(size_t)k * N_NODES + i] = s;
            s += hv;
        }
    }
    if (blockIdx.x == 0 && tid == 0) offsets[n] = cexcl[NCHUNKS];
}

// Packed CSR: entry = src (16 bits) | bf16 weight << 16;
// slot = offsets[c] + counts4excl[e&3][c] + rank[e] (atomic-free).
// 2 independent edges/thread for ILP.
__global__ __launch_bounds__(256) void fill_csr_kernel(const int* __restrict__ row,
                                                       const int* __restrict__ col,
                                                       const int* __restrict__ offsets,
                                                       const int* __restrict__ counts4,
                                                       const int* __restrict__ rank,
                                                       const float* __restrict__ dinv,
                                                       unsigned int* __restrict__ csr_ew) {
    int e0 = blockIdx.x * 512 + threadIdx.x;
    int e1 = e0 + 256;
    int c0 = -1, c1 = -1, r0 = 0, r1 = 0, k0 = 0, k1 = 0;
    if (e0 < N_EDGES) { c0 = col[e0]; r0 = row[e0]; k0 = rank[e0]; }
    if (e1 < N_EDGES) { c1 = col[e1]; r1 = row[e1]; k1 = rank[e1]; }
    float dc0 = 0.f, dr0 = 0.f, dc1 = 0.f, dr1 = 0.f;
    int h0 = 0, h1 = 0;
    if (c0 >= 0) {
        dc0 = dinv[c0]; dr0 = dinv[r0];
        h0 = counts4[(size_t)(e0 & 3) * N_NODES + c0];
    }
    if (c1 >= 0) {
        dc1 = dinv[c1]; dr1 = dinv[r1];
        h1 = counts4[(size_t)(e1 & 3) * N_NODES + c1];
    }
    if (c0 >= 0)
        csr_ew[offsets[c0] + h0 + k0] = (unsigned int)r0 | ((unsigned int)f2bf(dc0 * dr0) << 16);
    if (c1 >= 0)
        csr_ew[offsets[c1] + h1 + k1] = (unsigned int)r1 | ((unsigned int)f2bf(dc1 * dr1) << 16);
}

// ------------------------------------------------------------------
// fp8 MFMA GEMM: C[N_PAD x 256] = A[N_PAD x K] @ Bt^T   (Bt is [256][K], fp8)
// 128x128 tile / block (4 waves 2x2), BK=128, async global_load_lds staging.
// ------------------------------------------------------------------
template <int K, bool RELU>
__global__ __launch_bounds__(256) void gemm_fp8(const u8* __restrict__ A,
                                                const u8* __restrict__ Bt,
                                                u8* __restrict__ C) {
    __shared__ u8 As[4 * 4096];
    __shared__ u8 Bs[4 * 4096];
    int tid = threadIdx.x;
    int lane = tid & 63;
    int w = tid >> 6;
    int wm = w & 1, wn = w >> 1;
    int l16 = lane & 15, quad = lane >> 4;
    int row0 = blockIdx.x * 128;
    int col0 = blockIdx.y * 128;
    f32x4 acc[4][4] = {};

    int sr = tid >> 1;             // staging row 0..127
    int sh = (tid & 1) * 16;       // half-plane-row byte offset
    const u8* ga = A + (size_t)(row0 + sr) * K + sh;
    const u8* gb = Bt + (size_t)(col0 + sr) * K + sh;

    #pragma unroll
    for (int k0 = 0; k0 < K; k0 += 128) {
        if (k0) __syncthreads();
        #pragma unroll
        for (int q = 0; q < 4; ++q) {   // k-plane within stage
            gl2lds16(ga + k0 + q * 32, As + q * 4096 + w * 1024);
            gl2lds16(gb + k0 + q * 32, Bs + q * 4096 + w * 1024);
        }
        __syncthreads();
        #pragma unroll
        for (int h = 0; h < 4; ++h) {
            long af[4], bfr[4];
            #pragma unroll
            for (int i = 0; i < 4; ++i)
                af[i] = *(const long*)&As[h * 4096 + (wm * 64 + i * 16 + l16) * 32 + quad * 8];
            #pragma unroll
            for (int j = 0; j < 4; ++j)
                bfr[j] = *(const long*)&Bs[h * 4096 + (wn * 64 + j * 16 + l16) * 32 + quad * 8];
            #pragma unroll
            for (int i = 0; i < 4; ++i)
                #pragma unroll
                for (int j = 0; j < 4; ++j)
                    acc[i][j] = __builtin_amdgcn_mfma_f32_16x16x32_fp8_fp8(af[i], bfr[j], acc[i][j], 0, 0, 0);
        }
    }
    // epilogue: C/D layout col=lane&15, row=quad*4+reg (dtype-independent)
    #pragma unroll
    for (int i = 0; i < 4; ++i) {
        int rowb = row0 + wm * 64 + i * 16 + quad * 4;
        #pragma unroll
        for (int r = 0; r < 4; ++r) {
            int grow = rowb + r;
            #pragma unroll
            for (int j = 0; j < 4; ++j) {
                int gcol = col0 + wn * 64 + j * 16 + l16;
                float v = acc[i][j][r];
                if (RELU) v = fmaxf(v, 0.f);
                C[(size_t)grow * H_F + gcol] = f32_fp8(v);
            }
        }
    }
}

// ------------------------------------------------------------------
// GCN aggregation, 128-ch fp8 (layer-0, pre-GEMM), NO relu.
// ------------------------------------------------------------------
__global__ __launch_bounds__(256) void aggregate128(const u8* __restrict__ hw,
                                                    const float* __restrict__ dinv,
                                                    const int* __restrict__ offsets,
                                                    const unsigned int* __restrict__ csr_ew,
                                                    u8* __restrict__ hout) {
    int w = threadIdx.x >> 6;
    int lane = threadIdx.x & 63;
    int i = blockIdx.x * 4 + w;
    if (i >= N_NODES) return;
    float di = dinv[i];
    const u8* base = hw + (size_t)lane * 2;
    unsigned int su = *(const unsigned short*)(base + (size_t)i * IN_F);
    f32x2 sv = fp8x2_f32_lo(su);
    float s = di * di;
    float a0 = s * sv.x, a1 = s * sv.y;
    int t = __builtin_amdgcn_readfirstlane(offsets[i]);
    int end = __builtin_amdgcn_readfirstlane(offsets[i + 1]);
    if (t < end) {
        uint4 eA = *(const uint4*)(csr_ew + t);
        uint4 eB = *(const uint4*)(csr_ew + t + 4);
        for (; t < end; t += 8) {
            uint4 nA, nB;
            if (t + 8 < end) {
                nA = *(const uint4*)(csr_ew + t + 8);
                nB = *(const uint4*)(csr_ew + t + 12);
            }
            unsigned int e[8] = {eA.x, eA.y, eA.z, eA.w, eB.x, eB.y, eB.z, eB.w};
            unsigned int v[8];
            #pragma unroll
            for (int u = 0; u < 8; ++u)
                v[u] = *(const unsigned short*)(base + (size_t)(e[u] & 0xffff) * IN_F);
            #pragma unroll
            for (int u = 0; u < 8; ++u) {
                float wq = bf2f((ushort)(e[u] >> 16));
                f32x2 f = fp8x2_f32_lo(v[u]);
                a0 += wq * f.x; a1 += wq * f.y;
            }
            eA = nA; eB = nB;
        }
    }
    unsigned int o = f32_fp8x2_lo(a0, a1, 0u);
    *(unsigned short*)(hout + (size_t)i * IN_F + lane * 2) = (unsigned short)(o & 0xffff);
}

// ------------------------------------------------------------------
// GCN aggregation, 256-ch fp8, + relu. Padded, pipelined, scalar descr.
// ------------------------------------------------------------------
__global__ __launch_bounds__(256) void aggregate256(const u8* __restrict__ hw,
                                                    const float* __restrict__ dinv,
                                                    const int* __restrict__ offsets,
                                                    const unsigned int* __restrict__ csr_ew,
                                                    u8* __restrict__ hout) {
    int w = threadIdx.x >> 6;
    int lane = threadIdx.x & 63;
    int i = blockIdx.x * 4 + w;
    if (i >= N_NODES) return;
    float di = dinv[i];
    const u8* base = hw + (size_t)lane * 4;
    unsigned int su = *(const unsigned int*)(base + (size_t)i * H_F);
    f32x2 slo = fp8x2_f32_lo(su), shi = fp8x2_f32_hi(su);
    float s = di * di;
    float a0 = s * slo.x, a1 = s * slo.y, a2 = s * shi.x, a3 = s * shi.y;
    int t = __builtin_amdgcn_readfirstlane(offsets[i]);
    int end = __builtin_amdgcn_readfirstlane(offsets[i + 1]);
    if (t < end) {
        uint4 eA = *(const uint4*)(csr_ew + t);
        uint4 eB = *(const uint4*)(csr_ew + t + 4);
        for (; t < end; t += 8) {
            uint4 nA, nB;
            if (t + 8 < end) {
                nA = *(const uint4*)(csr_ew + t + 8);
                nB = *(const uint4*)(csr_ew + t + 12);
            }
            unsigned int e[8] = {eA.x, eA.y, eA.z, eA.w, eB.x, eB.y, eB.z, eB.w};
            unsigned int v[8];
            #pragma unroll
            for (int u = 0; u < 8; ++u)
                v[u] = *(const unsigned int*)(base + (size_t)(e[u] & 0xffff) * H_F);
            #pragma unroll
            for (int u = 0; u < 8; ++u) {
                float wq = bf2f((ushort)(e[u] >> 16));
                f32x2 lo = fp8x2_f32_lo(v[u]), hi = fp8x2_f32_hi(v[u]);
                a0 += wq * lo.x; a1 += wq * lo.y;
                a2 += wq * hi.x; a3 += wq * hi.y;
            }
            eA = nA; eB = nB;
        }
    }
    unsigned int o = f32_fp8x2_lo(fmaxf(a0, 0.f), fmaxf(a1, 0.f), 0u);
    o = f32_fp8x2_hi(fmaxf(a2, 0.f), fmaxf(a3, 0.f), o);
    *(unsigned int*)(hout + (size_t)i * H_F + lane * 4) = o;
}

// ------------------------------------------------------------------
// Fused pool + MLP head: one 1024-thread block (16 waves) per graph.
// ------------------------------------------------------------------
__global__ __launch_bounds__(1024) void pool_mlp_kernel(const u8* __restrict__ h,
                                                        const int* __restrict__ gstart,
                                                        const float* __restrict__ Wm1,
                                                        const float* __restrict__ bm1,
                                                        const float* __restrict__ Wm2,
                                                        const float* __restrict__ bm2,
                                                        float* __restrict__ out) {
    __shared__ float sm[16][H_F];
    __shared__ float p[H_F];
    __shared__ float hmid[H_F];
    __shared__ float lastv[OUT_F];
    __shared__ float stats[2];
    int g = blockIdx.x;
    int s = gstart[g], e = gstart[g + 1];
    int w = threadIdx.x >> 6;        // 0..15
    int lane = threadIdx.x & 63;
    float a0 = 0.f, a1 = 0.f, a2 = 0.f, a3 = 0.f;
    for (int i = s + w; i < e; i += 16) {
        unsigned int v = *(const unsigned int*)(h + (size_t)i * H_F + lane * 4);
        f32x2 lo = fp8x2_f32_lo(v), hi = fp8x2_f32_hi(v);
        a0 += lo.x; a1 += lo.y; a2 += hi.x; a3 += hi.y;
    }
    *(f32x4*)&sm[w][lane * 4] = (f32x4){a0, a1, a2, a3};
    __syncthreads();
    int j = threadIdx.x;
    int cnt = e - s;
    if (j < H_F) {
        float t = 0.f;
        #pragma unroll
        for (int k = 0; k < 16; ++k) t += sm[k][j];
        p[j] = t / (float)max(cnt, 1);
    }
    __syncthreads();
    if (j < H_F) {
        float acc = bm1[j];
        for (int k = 0; k < H_F; ++k) acc += p[k] * Wm1[k * H_F + j];
        hmid[j] = fmaxf(acc, 0.f);
    }
    __syncthreads();
    if (j < OUT_F) {
        float a = bm2[j];
        for (int k = 0; k < H_F; ++k) a += hmid[k] * Wm2[k * OUT_F + j];
        lastv[j] = a;
    }
    __syncthreads();
    if (j == 0) {
        float m = -1e30f;
        for (int o = 0; o < OUT_F; ++o) m = fmaxf(m, lastv[o]);
        float sxp = 0.f;
        for (int o = 0; o < OUT_F; ++o) sxp += expf(lastv[o] - m);
        stats[0] = m; stats[1] = logf(sxp);
    }
    __syncthreads();
    if (j < OUT_F) {
        float v = lastv[j];
        out[g * OUT_F + j] = v - stats[0] - stats[1];
        out[(size_t)N_G * OUT_F + g * OUT_F + j] = 1.f / (1.f + expf(-v));
        out[(size_t)2 * N_G * OUT_F + g * OUT_F + j] = v;
    }
}

// ------------------------------------------------------------------
extern "C" void kernel_launch(void* const* d_in, const int* in_sizes, int n_in,
                              void* d_out, int out_size, void* d_ws, size_t ws_size,
                              hipStream_t stream) {
    const float* x   = (const float*)d_in[0];
    const int* edge_index = (const int*)d_in[1];
    const int* batch = (const int*)d_in[3];
    const float* W0  = (const float*)d_in[4];
    const float* W1  = (const float*)d_in[5];
    const float* W2  = (const float*)d_in[6];
    const float* Wm1 = (const float*)d_in[7];
    const float* bm1 = (const float*)d_in[8];
    const float* Wm2 = (const float*)d_in[9];
    const float* bm2 = (const float*)d_in[10];
    float* out = (float*)d_out;

    char* ws = (char*)d_ws;
    size_t off = 0;
    auto alloc = [&](size_t bytes) -> void* {
        void* p = ws + off; off += (bytes + 255) & ~(size_t)255; return p;
    };
    u8* xb       = (u8*)alloc((size_t)N_PAD * IN_F);
    u8* bufA     = (u8*)alloc((size_t)N_PAD * H_F);
    u8* bufB     = (u8*)alloc((size_t)N_PAD * H_F);
    u8* t0       = (u8*)alloc((size_t)N_PAD * IN_F);
    u8* W0t      = (u8*)alloc((size_t)H_F * IN_F);
    u8* W1t      = (u8*)alloc((size_t)H_F * H_F);
    u8* W2t      = (u8*)alloc((size_t)H_F * H_F);
    float* dinv    = (float*)alloc((size_t)N_NODES * 4);
    int*   counts  = (int*)alloc((size_t)N_NODES * 4);
    int*   counts4 = (int*)alloc((size_t)NCOPY * N_NODES * 4);
    int*   offsets = (int*)alloc((size_t)(N_NODES + 1) * 4);
    int*   rank    = (int*)alloc((size_t)N_EDGES * 4);
    unsigned int* csr_ew = (unsigned int*)alloc((size_t)CSR_CAP * 4);
    int*   csum    = (int*)alloc((size_t)256 * 4);
    int*   gstart  = (int*)alloc((size_t)(N_G + 1) * 4);

    const int* row = edge_index;
    const int* col = edge_index + N_EDGES;

    hipMemsetAsync(counts4, 0, (size_t)NCOPY * N_NODES * 4, stream);

    prep_kernel<<<PREP_GS, 256, 0, stream>>>(col, counts4, rank, x, xb, W0, W0t,
                                             W1, W1t, W2, W2t, batch, gstart);
    chunk_reduce<<<NCHUNKS, 256, 0, stream>>>(counts4, counts, csum, N_NODES);
    scan_dinv_kernel<<<NCHUNKS, 256, 0, stream>>>(counts, csum, offsets, counts4,
                                                  dinv, csr_ew, N_NODES);
    fill_csr_kernel<<<1563, 256, 0, stream>>>(row, col, offsets, counts4, rank,
                                              dinv, csr_ew);

    dim3 gg(N_PAD / 128, H_F / 128);
    int agg_blocks = (N_NODES + 3) / 4;
    // layer 0: aggregate-first (linear ops commute), relu in GEMM epilogue
    aggregate128<<<agg_blocks, 256, 0, stream>>>(xb, dinv, offsets, csr_ew, t0);
    gemm_fp8<IN_F, true><<<gg, 256, 0, stream>>>(t0, W0t, bufA);
    // layer 1
    gemm_fp8<H_F, false><<<gg, 256, 0, stream>>>(bufA, W1t, bufB);
    aggregate256<<<agg_blocks, 256, 0, stream>>>(bufB, dinv, offsets, csr_ew, bufA);
    // layer 2
    gemm_fp8<H_F, false><<<gg, 256, 0, stream>>>(bufA, W2t, bufB);
    aggregate256<<<agg_blocks, 256, 0, stream>>>(bufB, dinv, offsets, csr_ew, bufA);

    pool_mlp_kernel<<<N_G, 1024, 0, stream>>>(bufA, gstart, Wm1, bm1, Wm2, bm2, out);
}

// Round 10
// 278.736 us; speedup vs baseline: 1.1321x; 1.0439x over previous
//
#include <hip/hip_runtime.h>
#include <math.h>

#define N_NODES 50000
#define N_PAD   50048          // padded to multiple of 128 for GEMM tiles
#define N_EDGES 800000
#define CSR_CAP 1200000        // >= sum pad8(deg) <= 800000 + 50000*7
#define IN_F 128
#define H_F 256
#define OUT_F 10
#define N_G 128
#define NCHUNKS 196            // ceil(N_NODES/256)

// LDS-histogram geometry: 256 blocks, each owns a contiguous edge slice
#define HB 256                 // histo blocks
#define EPB (N_EDGES / HB)     // 3125 edges per block (exact)
#define HWORDS (N_NODES / 2)   // 25000 packed dwords = 100 KB LDS

typedef __attribute__((ext_vector_type(4))) float f32x4;
typedef __attribute__((ext_vector_type(2))) float f32x2;
typedef unsigned char u8;
typedef unsigned short u16;

// ---- fp8 e4m3 (OCP) helpers: HW packed converts (imm word-select) ----
__device__ inline f32x2 fp8x2_f32_lo(unsigned int v) {
    return __builtin_amdgcn_cvt_pk_f32_fp8(v, false);
}
__device__ inline f32x2 fp8x2_f32_hi(unsigned int v) {
    return __builtin_amdgcn_cvt_pk_f32_fp8(v, true);
}
__device__ inline unsigned int f32_fp8x2_lo(float a, float b, unsigned int old) {
    return __builtin_amdgcn_cvt_pk_fp8_f32(a, b, old, false);
}
__device__ inline unsigned int f32_fp8x2_hi(float a, float b, unsigned int old) {
    return __builtin_amdgcn_cvt_pk_fp8_f32(a, b, old, true);
}
__device__ inline u8 f32_fp8(float a) {
    return (u8)(f32_fp8x2_lo(a, a, 0u) & 0xff);
}
// ---- bf16 helpers (packed CSR weight) ----
__device__ inline ushort f2bf(float x) {
    union { float f; unsigned int u; } v; v.f = x;
    unsigned int r = v.u + 0x7fff + ((v.u >> 16) & 1);
    return (ushort)(r >> 16);
}
__device__ inline float bf2f(ushort u) {
    union { unsigned int u; float f; } v; v.u = ((unsigned int)u) << 16; return v.f;
}

// async global->LDS, 16 B per lane; lds dest = wave-uniform base + lane*16
__device__ inline void gl2lds16(const void* g, void* l) {
    __builtin_amdgcn_global_load_lds(
        (const __attribute__((address_space(1))) unsigned int*)g,
        (__attribute__((address_space(3))) unsigned int*)l,
        16, 0, 0);
}

// ------------------------------------------------------------------
// LDS histogram: 256 blocks, each counts its 3125-edge slice over the
// FULL node range in 16-bit-packed LDS counters (100 KB, dynamic).
// NO global atomics. rank[e] = block-local rank from the packed
// atomic return (max count 3125 << 65536, low half never carries).
// Only ~13 main-loop iterations/block (R8 failed at 195: these loops
// run unpipelined at ~1 load-latency/iter).
// ------------------------------------------------------------------
__global__ __launch_bounds__(256) void histo_kernel(const int* __restrict__ col,
                                                    u16* __restrict__ H,
                                                    int* __restrict__ rank) {
    extern __shared__ unsigned int hcnt[];     // HWORDS dwords = 100 KB
    int b = blockIdx.x;
    int tid = threadIdx.x;
    for (int j = tid; j < HWORDS; j += 256) hcnt[j] = 0u;
    __syncthreads();
    int e0 = b * EPB, e1 = e0 + EPB;
    for (int e = e0 + tid; e < e1; e += 256) {
        int c = col[e];
        int sh = (c & 1) << 4;
        unsigned int old = atomicAdd(&hcnt[c >> 1], 1u << sh);
        rank[e] = (int)((old >> sh) & 0xffffu);
    }
    __syncthreads();
    u16* Hrow = H + (size_t)b * N_NODES;
    for (int j = tid; j < HWORDS; j += 256)
        *(unsigned int*)&Hrow[j * 2] = hcnt[j];
}

// ------------------------------------------------------------------
// Fused: chunk-prefix (blocks 0..195) + fp8 converts + graph starts.
// chunk role: per node i, turn H[b][i] into the EXCLUSIVE prefix over
// b (in place, manual 8-wide unroll keeps 8 loads in flight), emit
// counts[i] (total degree) and per-chunk padded sums (csum).
// ------------------------------------------------------------------
#define CC_CHUNK 196
#define CC_X    (CC_CHUNK + 6250)
#define CC_T0   (CC_X + 128)
#define CC_T1   (CC_T0 + 256)
#define CC_T2   (CC_T1 + 256)
#define CC_GS   (CC_T2 + NCHUNKS)

__global__ __launch_bounds__(256) void convert_chunk_kernel(
    u16* __restrict__ H, int* __restrict__ counts, int* __restrict__ csum,
    const float* __restrict__ x, u8* __restrict__ xb,
    const float* __restrict__ W0, u8* __restrict__ W0t,
    const float* __restrict__ W1, u8* __restrict__ W1t,
    const float* __restrict__ W2, u8* __restrict__ W2t,
    const int* __restrict__ batch, int* __restrict__ gstart) {
    int b = blockIdx.x;
    int tid = threadIdx.x;
    if (b < CC_CHUNK) {
        int i = b * 256 + tid;
        int total = 0;
        if (i < N_NODES) {
            u16* ci = H + i;
            int s = 0;
            for (int b0 = 0; b0 < HB; b0 += 8) {
                int h[8];
                #pragma unroll
                for (int u = 0; u < 8; ++u)
                    h[u] = ci[(size_t)(b0 + u) * N_NODES];
                #pragma unroll
                for (int u = 0; u < 8; ++u) {
                    ci[(size_t)(b0 + u) * N_NODES] = (u16)s;
                    s += h[u];
                }
            }
            total = s;
            counts[i] = total;
        }
        int v = (i < N_NODES) ? ((total + 7) & ~7) : 0;
        #pragma unroll
        for (int off = 32; off; off >>= 1) v += __shfl_down(v, off);
        __shared__ int ws[4];
        if ((tid & 63) == 0) ws[tid >> 6] = v;
        __syncthreads();
        if (tid == 0) csum[b] = ws[0] + ws[1] + ws[2] + ws[3];
    } else if (b < CC_X) {
        int i = (b - CC_CHUNK) * 256 + tid;     // < 1,600,000 exactly
        float4 v = *(const float4*)(x + (size_t)i * 4);
        unsigned int p = f32_fp8x2_lo(v.x, v.y, 0u);
        p = f32_fp8x2_hi(v.z, v.w, p);
        *(unsigned int*)(xb + (size_t)i * 4) = p;
    } else if (b < CC_T0) {
        int idx = (b - CC_X) * 256 + tid;       // < 32768
        int k = idx >> 8, nn = idx & 255;       // K=128, Nc=256
        W0t[nn * IN_F + k] = f32_fp8(W0[idx]);
    } else if (b < CC_T1) {
        int idx = (b - CC_T0) * 256 + tid;      // < 65536
        int k = idx >> 8, nn = idx & 255;
        W1t[nn * H_F + k] = f32_fp8(W1[idx]);
    } else if (b < CC_T2) {
        int idx = (b - CC_T1) * 256 + tid;
        int k = idx >> 8, nn = idx & 255;
        W2t[nn * H_F + k] = f32_fp8(W2[idx]);
    } else {
        int i = (b - CC_T2) * 256 + tid;
        if (i >= N_NODES) return;
        int bb = batch[i];
        if (i == 0) {
            for (int g = 0; g <= bb; ++g) gstart[g] = 0;
        } else {
            int p = batch[i - 1];
            if (p != bb) { for (int g = p + 1; g <= bb; ++g) gstart[g] = i; }
        }
        if (i == N_NODES - 1) {
            for (int g = bb + 1; g <= N_G; ++g) gstart[g] = N_NODES;
        }
    }
}

// ------------------------------------------------------------------
// scan (over padded counts, csum-based block base) + dinv + zero
// padding CSR slots. (Verified R6 form.)
// ------------------------------------------------------------------
__global__ __launch_bounds__(256) void scan_dinv_kernel(const int* __restrict__ counts,
                                                        const int* __restrict__ csum,
                                                        int* __restrict__ offsets,
                                                        float* __restrict__ dinv,
                                                        unsigned int* __restrict__ csr_ew,
                                                        int n) {
    int tid = threadIdx.x;
    int lane = tid & 63, wid = tid >> 6;
    int cv = (tid < NCHUNKS) ? csum[tid] : 0;
    int xc = cv;
    #pragma unroll
    for (int off = 1; off < 64; off <<= 1) {
        int t = __shfl_up(xc, off);
        if (lane >= off) xc += t;
    }
    __shared__ int cw[4], cpre[4];
    __shared__ int cexcl[257];
    if (lane == 63) cw[wid] = xc;
    __syncthreads();
    if (tid == 0) { int s = 0; for (int k = 0; k < 4; ++k) { cpre[k] = s; s += cw[k]; } }
    __syncthreads();
    cexcl[tid] = cpre[wid] + xc - cv;
    if (tid == 255) cexcl[256] = cpre[3] + cw[3];
    __syncthreads();
    int base = cexcl[blockIdx.x];
    int i = blockIdx.x * 256 + tid;
    int v = (i < n) ? counts[i] : 0;
    int pv = (v + 7) & ~7;
    int x = pv;
    #pragma unroll
    for (int off = 1; off < 64; off <<= 1) {
        int t = __shfl_up(x, off);
        if (lane >= off) x += t;
    }
    __shared__ int wsum[4], wpre[4];
    if (lane == 63) wsum[wid] = x;
    __syncthreads();
    if (tid == 0) { int s = 0; for (int k = 0; k < 4; ++k) { wpre[k] = s; s += wsum[k]; } }
    __syncthreads();
    if (i < n) {
        int o = base + wpre[wid] + x - pv;       // exclusive, padded
        offsets[i] = o;
        dinv[i] = rsqrtf((float)(v + 1));
        for (int z = v; z < pv; ++z) csr_ew[o + z] = 0u;   // zero padding slots
    }
    if (blockIdx.x == 0 && tid == 0) offsets[n] = cexcl[NCHUNKS];
}

// Packed CSR: entry = src (16 bits) | bf16 weight << 16;
// slot = offsets[c] + Hexcl[e/EPB][c] + rank[e] (fully atomic-free).
// 2 independent edges/thread for ILP.
__global__ __launch_bounds__(256) void fill_csr_kernel(const int* __restrict__ row,
                                                       const int* __restrict__ col,
                                                       const int* __restrict__ offsets,
                                                       const u16* __restrict__ H,
                                                       const int* __restrict__ rank,
                                                       const float* __restrict__ dinv,
                                                       unsigned int* __restrict__ csr_ew) {
    int e0 = blockIdx.x * 512 + threadIdx.x;
    int e1 = e0 + 256;
    int c0 = -1, c1 = -1, r0 = 0, r1 = 0, k0 = 0, k1 = 0;
    if (e0 < N_EDGES) { c0 = col[e0]; r0 = row[e0]; k0 = rank[e0]; }
    if (e1 < N_EDGES) { c1 = col[e1]; r1 = row[e1]; k1 = rank[e1]; }
    float dc0 = 0.f, dr0 = 0.f, dc1 = 0.f, dr1 = 0.f;
    int h0 = 0, h1 = 0;
    if (c0 >= 0) {
        dc0 = dinv[c0]; dr0 = dinv[r0];
        h0 = (int)H[(size_t)(e0 / EPB) * N_NODES + c0];
    }
    if (c1 >= 0) {
        dc1 = dinv[c1]; dr1 = dinv[r1];
        h1 = (int)H[(size_t)(e1 / EPB) * N_NODES + c1];
    }
    if (c0 >= 0)
        csr_ew[offsets[c0] + h0 + k0] = (unsigned int)r0 | ((unsigned int)f2bf(dc0 * dr0) << 16);
    if (c1 >= 0)
        csr_ew[offsets[c1] + h1 + k1] = (unsigned int)r1 | ((unsigned int)f2bf(dc1 * dr1) << 16);
}

// ------------------------------------------------------------------
// fp8 MFMA GEMM: C[N_PAD x 256] = A[N_PAD x K] @ Bt^T   (Bt is [256][K], fp8)
// 128x128 tile / block (4 waves 2x2), BK=128, async global_load_lds staging.
// ------------------------------------------------------------------
template <int K, bool RELU>
__global__ __launch_bounds__(256) void gemm_fp8(const u8* __restrict__ A,
                                                const u8* __restrict__ Bt,
                                                u8* __restrict__ C) {
    __shared__ u8 As[4 * 4096];
    __shared__ u8 Bs[4 * 4096];
    int tid = threadIdx.x;
    int lane = tid & 63;
    int w = tid >> 6;
    int wm = w & 1, wn = w >> 1;
    int l16 = lane & 15, quad = lane >> 4;
    int row0 = blockIdx.x * 128;
    int col0 = blockIdx.y * 128;
    f32x4 acc[4][4] = {};

    int sr = tid >> 1;             // staging row 0..127
    int sh = (tid & 1) * 16;       // half-plane-row byte offset
    const u8* ga = A + (size_t)(row0 + sr) * K + sh;
    const u8* gb = Bt + (size_t)(col0 + sr) * K + sh;

    #pragma unroll
    for (int k0 = 0; k0 < K; k0 += 128) {
        if (k0) __syncthreads();
        #pragma unroll
        for (int q = 0; q < 4; ++q) {   // k-plane within stage
            gl2lds16(ga + k0 + q * 32, As + q * 4096 + w * 1024);
            gl2lds16(gb + k0 + q * 32, Bs + q * 4096 + w * 1024);
        }
        __syncthreads();
        #pragma unroll
        for (int h = 0; h < 4; ++h) {
            long af[4], bfr[4];
            #pragma unroll
            for (int i = 0; i < 4; ++i)
                af[i] = *(const long*)&As[h * 4096 + (wm * 64 + i * 16 + l16) * 32 + quad * 8];
            #pragma unroll
            for (int j = 0; j < 4; ++j)
                bfr[j] = *(const long*)&Bs[h * 4096 + (wn * 64 + j * 16 + l16) * 32 + quad * 8];
            #pragma unroll
            for (int i = 0; i < 4; ++i)
                #pragma unroll
                for (int j = 0; j < 4; ++j)
                    acc[i][j] = __builtin_amdgcn_mfma_f32_16x16x32_fp8_fp8(af[i], bfr[j], acc[i][j], 0, 0, 0);
        }
    }
    // epilogue: C/D layout col=lane&15, row=quad*4+reg (dtype-independent)
    #pragma unroll
    for (int i = 0; i < 4; ++i) {
        int rowb = row0 + wm * 64 + i * 16 + quad * 4;
        #pragma unroll
        for (int r = 0; r < 4; ++r) {
            int grow = rowb + r;
            #pragma unroll
            for (int j = 0; j < 4; ++j) {
                int gcol = col0 + wn * 64 + j * 16 + l16;
                float v = acc[i][j][r];
                if (RELU) v = fmaxf(v, 0.f);
                C[(size_t)grow * H_F + gcol] = f32_fp8(v);
            }
        }
    }
}

// ------------------------------------------------------------------
// GCN aggregation, 128-ch fp8 (layer-0, pre-GEMM), NO relu.
// ------------------------------------------------------------------
__global__ __launch_bounds__(256) void aggregate128(const u8* __restrict__ hw,
                                                    const float* __restrict__ dinv,
                                                    const int* __restrict__ offsets,
                                                    const unsigned int* __restrict__ csr_ew,
                                                    u8* __restrict__ hout) {
    int w = threadIdx.x >> 6;
    int lane = threadIdx.x & 63;
    int i = blockIdx.x * 4 + w;
    if (i >= N_NODES) return;
    float di = dinv[i];
    const u8* base = hw + (size_t)lane * 2;
    unsigned int su = *(const unsigned short*)(base + (size_t)i * IN_F);
    f32x2 sv = fp8x2_f32_lo(su);
    float s = di * di;
    float a0 = s * sv.x, a1 = s * sv.y;
    int t = __builtin_amdgcn_readfirstlane(offsets[i]);
    int end = __builtin_amdgcn_readfirstlane(offsets[i + 1]);
    if (t < end) {
        uint4 eA = *(const uint4*)(csr_ew + t);
        uint4 eB = *(const uint4*)(csr_ew + t + 4);
        for (; t < end; t += 8) {
            uint4 nA, nB;
            if (t + 8 < end) {
                nA = *(const uint4*)(csr_ew + t + 8);
                nB = *(const uint4*)(csr_ew + t + 12);
            }
            unsigned int e[8] = {eA.x, eA.y, eA.z, eA.w, eB.x, eB.y, eB.z, eB.w};
            unsigned int v[8];
            #pragma unroll
            for (int u = 0; u < 8; ++u)
                v[u] = *(const unsigned short*)(base + (size_t)(e[u] & 0xffff) * IN_F);
            #pragma unroll
            for (int u = 0; u < 8; ++u) {
                float wq = bf2f((ushort)(e[u] >> 16));
                f32x2 f = fp8x2_f32_lo(v[u]);
                a0 += wq * f.x; a1 += wq * f.y;
            }
            eA = nA; eB = nB;
        }
    }
    unsigned int o = f32_fp8x2_lo(a0, a1, 0u);
    *(unsigned short*)(hout + (size_t)i * IN_F + lane * 2) = (unsigned short)(o & 0xffff);
}

// ------------------------------------------------------------------
// GCN aggregation, 256-ch fp8, + relu. Padded, pipelined, scalar descr.
// ------------------------------------------------------------------
__global__ __launch_bounds__(256) void aggregate256(const u8* __restrict__ hw,
                                                    const float* __restrict__ dinv,
                                                    const int* __restrict__ offsets,
                                                    const unsigned int* __restrict__ csr_ew,
                                                    u8* __restrict__ hout) {
    int w = threadIdx.x >> 6;
    int lane = threadIdx.x & 63;
    int i = blockIdx.x * 4 + w;
    if (i >= N_NODES) return;
    float di = dinv[i];
    const u8* base = hw + (size_t)lane * 4;
    unsigned int su = *(const unsigned int*)(base + (size_t)i * H_F);
    f32x2 slo = fp8x2_f32_lo(su), shi = fp8x2_f32_hi(su);
    float s = di * di;
    float a0 = s * slo.x, a1 = s * slo.y, a2 = s * shi.x, a3 = s * shi.y;
    int t = __builtin_amdgcn_readfirstlane(offsets[i]);
    int end = __builtin_amdgcn_readfirstlane(offsets[i + 1]);
    if (t < end) {
        uint4 eA = *(const uint4*)(csr_ew + t);
        uint4 eB = *(const uint4*)(csr_ew + t + 4);
        for (; t < end; t += 8) {
            uint4 nA, nB;
            if (t + 8 < end) {
                nA = *(const uint4*)(csr_ew + t + 8);
                nB = *(const uint4*)(csr_ew + t + 12);
            }
            unsigned int e[8] = {eA.x, eA.y, eA.z, eA.w, eB.x, eB.y, eB.z, eB.w};
            unsigned int v[8];
            #pragma unroll
            for (int u = 0; u < 8; ++u)
                v[u] = *(const unsigned int*)(base + (size_t)(e[u] & 0xffff) * H_F);
            #pragma unroll
            for (int u = 0; u < 8; ++u) {
                float wq = bf2f((ushort)(e[u] >> 16));
                f32x2 lo = fp8x2_f32_lo(v[u]), hi = fp8x2_f32_hi(v[u]);
                a0 += wq * lo.x; a1 += wq * lo.y;
                a2 += wq * hi.x; a3 += wq * hi.y;
            }
            eA = nA; eB = nB;
        }
    }
    unsigned int o = f32_fp8x2_lo(fmaxf(a0, 0.f), fmaxf(a1, 0.f), 0u);
    o = f32_fp8x2_hi(fmaxf(a2, 0.f), fmaxf(a3, 0.f), o);
    *(unsigned int*)(hout + (size_t)i * H_F + lane * 4) = o;
}

// ------------------------------------------------------------------
// Fused pool + MLP head: one 1024-thread block (16 waves) per graph.
// ------------------------------------------------------------------
__global__ __launch_bounds__(1024) void pool_mlp_kernel(const u8* __restrict__ h,
                                                        const int* __restrict__ gstart,
                                                        const float* __restrict__ Wm1,
                                                        const float* __restrict__ bm1,
                                                        const float* __restrict__ Wm2,
                                                        const float* __restrict__ bm2,
                                                        float* __restrict__ out) {
    __shared__ float sm[16][H_F];
    __shared__ float p[H_F];
    __shared__ float hmid[H_F];
    __shared__ float lastv[OUT_F];
    __shared__ float stats[2];
    int g = blockIdx.x;
    int s = gstart[g], e = gstart[g + 1];
    int w = threadIdx.x >> 6;        // 0..15
    int lane = threadIdx.x & 63;
    float a0 = 0.f, a1 = 0.f, a2 = 0.f, a3 = 0.f;
    for (int i = s + w; i < e; i += 16) {
        unsigned int v = *(const unsigned int*)(h + (size_t)i * H_F + lane * 4);
        f32x2 lo = fp8x2_f32_lo(v), hi = fp8x2_f32_hi(v);
        a0 += lo.x; a1 += lo.y; a2 += hi.x; a3 += hi.y;
    }
    *(f32x4*)&sm[w][lane * 4] = (f32x4){a0, a1, a2, a3};
    __syncthreads();
    int j = threadIdx.x;
    int cnt = e - s;
    if (j < H_F) {
        float t = 0.f;
        #pragma unroll
        for (int k = 0; k < 16; ++k) t += sm[k][j];
        p[j] = t / (float)max(cnt, 1);
    }
    __syncthreads();
    if (j < H_F) {
        float acc = bm1[j];
        for (int k = 0; k < H_F; ++k) acc += p[k] * Wm1[k * H_F + j];
        hmid[j] = fmaxf(acc, 0.f);
    }
    __syncthreads();
    if (j < OUT_F) {
        float a = bm2[j];
        for (int k = 0; k < H_F; ++k) a += hmid[k] * Wm2[k * OUT_F + j];
        lastv[j] = a;
    }
    __syncthreads();
    if (j == 0) {
        float m = -1e30f;
        for (int o = 0; o < OUT_F; ++o) m = fmaxf(m, lastv[o]);
        float sxp = 0.f;
        for (int o = 0; o < OUT_F; ++o) sxp += expf(lastv[o] - m);
        stats[0] = m; stats[1] = logf(sxp);
    }
    __syncthreads();
    if (j < OUT_F) {
        float v = lastv[j];
        out[g * OUT_F + j] = v - stats[0] - stats[1];
        out[(size_t)N_G * OUT_F + g * OUT_F + j] = 1.f / (1.f + expf(-v));
        out[(size_t)2 * N_G * OUT_F + g * OUT_F + j] = v;
    }
}

// ------------------------------------------------------------------
extern "C" void kernel_launch(void* const* d_in, const int* in_sizes, int n_in,
                              void* d_out, int out_size, void* d_ws, size_t ws_size,
                              hipStream_t stream) {
    const float* x   = (const float*)d_in[0];
    const int* edge_index = (const int*)d_in[1];
    const int* batch = (const int*)d_in[3];
    const float* W0  = (const float*)d_in[4];
    const float* W1  = (const float*)d_in[5];
    const float* W2  = (const float*)d_in[6];
    const float* Wm1 = (const float*)d_in[7];
    const float* bm1 = (const float*)d_in[8];
    const float* Wm2 = (const float*)d_in[9];
    const float* bm2 = (const float*)d_in[10];
    float* out = (float*)d_out;

    char* ws = (char*)d_ws;
    size_t off = 0;
    auto alloc = [&](size_t bytes) -> void* {
        void* p = ws + off; off += (bytes + 255) & ~(size_t)255; return p;
    };
    u8* xb       = (u8*)alloc((size_t)N_PAD * IN_F);
    u8* bufA     = (u8*)alloc((size_t)N_PAD * H_F);
    u8* bufB     = (u8*)alloc((size_t)N_PAD * H_F);
    u8* t0       = (u8*)alloc((size_t)N_PAD * IN_F);
    u8* W0t      = (u8*)alloc((size_t)H_F * IN_F);
    u8* W1t      = (u8*)alloc((size_t)H_F * H_F);
    u8* W2t      = (u8*)alloc((size_t)H_F * H_F);
    float* dinv    = (float*)alloc((size_t)N_NODES * 4);
    int*   counts  = (int*)alloc((size_t)N_NODES * 4);
    int*   offsets = (int*)alloc((size_t)(N_NODES + 1) * 4);
    int*   rank    = (int*)alloc((size_t)N_EDGES * 4);
    u16*   H       = (u16*)alloc((size_t)HB * N_NODES * 2);
    unsigned int* csr_ew = (unsigned int*)alloc((size_t)CSR_CAP * 4);
    int*   csum    = (int*)alloc((size_t)256 * 4);
    int*   gstart  = (int*)alloc((size_t)(N_G + 1) * 4);

    const int* row = edge_index;
    const int* col = edge_index + N_EDGES;

    histo_kernel<<<HB, 256, HWORDS * 4, stream>>>(col, H, rank);
    convert_chunk_kernel<<<CC_GS, 256, 0, stream>>>(H, counts, csum, x, xb,
                                                    W0, W0t, W1, W1t, W2, W2t,
                                                    batch, gstart);
    scan_dinv_kernel<<<NCHUNKS, 256, 0, stream>>>(counts, csum, offsets, dinv,
                                                  csr_ew, N_NODES);
    fill_csr_kernel<<<1563, 256, 0, stream>>>(row, col, offsets, H, rank,
                                              dinv, csr_ew);

    dim3 gg(N_PAD / 128, H_F / 128);
    int agg_blocks = (N_NODES + 3) / 4;
    // layer 0: aggregate-first (linear ops commute), relu in GEMM epilogue
    aggregate128<<<agg_blocks, 256, 0, stream>>>(xb, dinv, offsets, csr_ew, t0);
    gemm_fp8<IN_F, true><<<gg, 256, 0, stream>>>(t0, W0t, bufA);
    // layer 1
    gemm_fp8<H_F, false><<<gg, 256, 0, stream>>>(bufA, W1t, bufB);
    aggregate256<<<agg_blocks, 256, 0, stream>>>(bufB, dinv, offsets, csr_ew, bufA);
    // layer 2
    gemm_fp8<H_F, false><<<gg, 256, 0, stream>>>(bufA, W2t, bufB);
    aggregate256<<<agg_blocks, 256, 0, stream>>>(bufB, dinv, offsets, csr_ew, bufA);

    pool_mlp_kernel<<<N_G, 1024, 0, stream>>>(bufA, gstart, Wm1, bm1, Wm2, bm2, out);
}

// Round 11
// 268.601 us; speedup vs baseline: 1.1748x; 1.0377x over previous
//
#include <hip/hip_runtime.h>
#include <math.h>

#define N_NODES 50000
#define N_PAD   50048          // padded to multiple of 128 for GEMM tiles
#define N_EDGES 800000
#define CSR_CAP 1200000        // >= sum pad8(deg) <= 800000 + 50000*7
#define IN_F 128
#define H_F 256
#define OUT_F 10
#define N_G 128
#define NCHUNKS 196            // ceil(N_NODES/256)

// LDS-histogram geometry: 256 blocks, each owns a contiguous edge slice
#define HB 256                 // histo blocks
#define EPB (N_EDGES / HB)     // 3125 edges per block (exact)
#define HWORDS (N_NODES / 4)   // 12500 packed dwords = 50 KB (u8 counters)

typedef __attribute__((ext_vector_type(4))) float f32x4;
typedef __attribute__((ext_vector_type(2))) float f32x2;
typedef unsigned char u8;

// ---- fp8 e4m3 (OCP) helpers: HW packed converts (imm word-select) ----
__device__ inline f32x2 fp8x2_f32_lo(unsigned int v) {
    return __builtin_amdgcn_cvt_pk_f32_fp8(v, false);
}
__device__ inline f32x2 fp8x2_f32_hi(unsigned int v) {
    return __builtin_amdgcn_cvt_pk_f32_fp8(v, true);
}
__device__ inline unsigned int f32_fp8x2_lo(float a, float b, unsigned int old) {
    return __builtin_amdgcn_cvt_pk_fp8_f32(a, b, old, false);
}
__device__ inline unsigned int f32_fp8x2_hi(float a, float b, unsigned int old) {
    return __builtin_amdgcn_cvt_pk_fp8_f32(a, b, old, true);
}
__device__ inline u8 f32_fp8(float a) {
    return (u8)(f32_fp8x2_lo(a, a, 0u) & 0xff);
}
// ---- bf16 helpers (packed CSR weight) ----
__device__ inline ushort f2bf(float x) {
    union { float f; unsigned int u; } v; v.f = x;
    unsigned int r = v.u + 0x7fff + ((v.u >> 16) & 1);
    return (ushort)(r >> 16);
}
__device__ inline float bf2f(ushort u) {
    union { unsigned int u; float f; } v; v.u = ((unsigned int)u) << 16; return v.f;
}

// async global->LDS, 16 B per lane; lds dest = wave-uniform base + lane*16
__device__ inline void gl2lds16(const void* g, void* l) {
    __builtin_amdgcn_global_load_lds(
        (const __attribute__((address_space(1))) unsigned int*)g,
        (__attribute__((address_space(3))) unsigned int*)l,
        16, 0, 0);
}

// ------------------------------------------------------------------
// LDS histogram: 256 blocks, each counts its 3125-edge slice over the
// FULL node range in u8-packed LDS counters (50 KB dynamic). NO global
// atomics, NO rank store (rank is re-derived in fill_csr). Max cell
// count ~6 (Binomial(3125,1/50000)), no byte carry possible.
// ------------------------------------------------------------------
__global__ __launch_bounds__(256) void histo_kernel(const int* __restrict__ col,
                                                    u8* __restrict__ H) {
    extern __shared__ unsigned int hcnt[];     // HWORDS dwords = 50 KB
    int b = blockIdx.x;
    int tid = threadIdx.x;
    for (int j = tid; j < HWORDS; j += 256) hcnt[j] = 0u;
    __syncthreads();
    int e0 = b * EPB, e1 = e0 + EPB;
    for (int e = e0 + tid; e < e1; e += 256) {
        int c = col[e];
        atomicAdd(&hcnt[c >> 2], 1u << ((c & 3) << 3));
    }
    __syncthreads();
    unsigned int* Hrow = (unsigned int*)(H + (size_t)b * N_NODES);
    for (int j = tid; j < HWORDS; j += 256) Hrow[j] = hcnt[j];
}

// ------------------------------------------------------------------
// Fused: chunk-prefix (blocks 0..195) + fp8 converts + graph starts.
// chunk role: per node i, turn H[b][i] (u8) into the EXCLUSIVE prefix
// over b (in place, 8-wide unroll keeps 8 loads in flight), emit
// counts[i] (total degree, <= ~60) and per-chunk padded sums (csum).
// ------------------------------------------------------------------
#define CC_CHUNK 196
#define CC_X    (CC_CHUNK + 6250)
#define CC_T0   (CC_X + 128)
#define CC_T1   (CC_T0 + 256)
#define CC_T2   (CC_T1 + 256)
#define CC_GS   (CC_T2 + NCHUNKS)

__global__ __launch_bounds__(256) void convert_chunk_kernel(
    u8* __restrict__ H, int* __restrict__ counts, int* __restrict__ csum,
    const float* __restrict__ x, u8* __restrict__ xb,
    const float* __restrict__ W0, u8* __restrict__ W0t,
    const float* __restrict__ W1, u8* __restrict__ W1t,
    const float* __restrict__ W2, u8* __restrict__ W2t,
    const int* __restrict__ batch, int* __restrict__ gstart) {
    int b = blockIdx.x;
    int tid = threadIdx.x;
    if (b < CC_CHUNK) {
        int i = b * 256 + tid;
        int total = 0;
        if (i < N_NODES) {
            u8* ci = H + i;
            int s = 0;
            for (int b0 = 0; b0 < HB; b0 += 8) {
                int h[8];
                #pragma unroll
                for (int u = 0; u < 8; ++u)
                    h[u] = ci[(size_t)(b0 + u) * N_NODES];
                #pragma unroll
                for (int u = 0; u < 8; ++u) {
                    ci[(size_t)(b0 + u) * N_NODES] = (u8)s;
                    s += h[u];
                }
            }
            total = s;
            counts[i] = total;
        }
        int v = (i < N_NODES) ? ((total + 7) & ~7) : 0;
        #pragma unroll
        for (int off = 32; off; off >>= 1) v += __shfl_down(v, off);
        __shared__ int ws[4];
        if ((tid & 63) == 0) ws[tid >> 6] = v;
        __syncthreads();
        if (tid == 0) csum[b] = ws[0] + ws[1] + ws[2] + ws[3];
    } else if (b < CC_X) {
        int i = (b - CC_CHUNK) * 256 + tid;     // < 1,600,000 exactly
        float4 v = *(const float4*)(x + (size_t)i * 4);
        unsigned int p = f32_fp8x2_lo(v.x, v.y, 0u);
        p = f32_fp8x2_hi(v.z, v.w, p);
        *(unsigned int*)(xb + (size_t)i * 4) = p;
    } else if (b < CC_T0) {
        int idx = (b - CC_X) * 256 + tid;       // < 32768
        int k = idx >> 8, nn = idx & 255;       // K=128, Nc=256
        W0t[nn * IN_F + k] = f32_fp8(W0[idx]);
    } else if (b < CC_T1) {
        int idx = (b - CC_T0) * 256 + tid;      // < 65536
        int k = idx >> 8, nn = idx & 255;
        W1t[nn * H_F + k] = f32_fp8(W1[idx]);
    } else if (b < CC_T2) {
        int idx = (b - CC_T1) * 256 + tid;
        int k = idx >> 8, nn = idx & 255;
        W2t[nn * H_F + k] = f32_fp8(W2[idx]);
    } else {
        int i = (b - CC_T2) * 256 + tid;
        if (i >= N_NODES) return;
        int bb = batch[i];
        if (i == 0) {
            for (int g = 0; g <= bb; ++g) gstart[g] = 0;
        } else {
            int p = batch[i - 1];
            if (p != bb) { for (int g = p + 1; g <= bb; ++g) gstart[g] = i; }
        }
        if (i == N_NODES - 1) {
            for (int g = bb + 1; g <= N_G; ++g) gstart[g] = N_NODES;
        }
    }
}

// ------------------------------------------------------------------
// scan (over padded counts, csum-based block base) + dinv + zero
// padding CSR slots. (Verified R6 form.)
// ------------------------------------------------------------------
__global__ __launch_bounds__(256) void scan_dinv_kernel(const int* __restrict__ counts,
                                                        const int* __restrict__ csum,
                                                        int* __restrict__ offsets,
                                                        float* __restrict__ dinv,
                                                        unsigned int* __restrict__ csr_ew,
                                                        int n) {
    int tid = threadIdx.x;
    int lane = tid & 63, wid = tid >> 6;
    int cv = (tid < NCHUNKS) ? csum[tid] : 0;
    int xc = cv;
    #pragma unroll
    for (int off = 1; off < 64; off <<= 1) {
        int t = __shfl_up(xc, off);
        if (lane >= off) xc += t;
    }
    __shared__ int cw[4], cpre[4];
    __shared__ int cexcl[257];
    if (lane == 63) cw[wid] = xc;
    __syncthreads();
    if (tid == 0) { int s = 0; for (int k = 0; k < 4; ++k) { cpre[k] = s; s += cw[k]; } }
    __syncthreads();
    cexcl[tid] = cpre[wid] + xc - cv;
    if (tid == 255) cexcl[256] = cpre[3] + cw[3];
    __syncthreads();
    int base = cexcl[blockIdx.x];
    int i = blockIdx.x * 256 + tid;
    int v = (i < n) ? counts[i] : 0;
    int pv = (v + 7) & ~7;
    int x = pv;
    #pragma unroll
    for (int off = 1; off < 64; off <<= 1) {
        int t = __shfl_up(x, off);
        if (lane >= off) x += t;
    }
    __shared__ int wsum[4], wpre[4];
    if (lane == 63) wsum[wid] = x;
    __syncthreads();
    if (tid == 0) { int s = 0; for (int k = 0; k < 4; ++k) { wpre[k] = s; s += wsum[k]; } }
    __syncthreads();
    if (i < n) {
        int o = base + wpre[wid] + x - pv;       // exclusive, padded
        offsets[i] = o;
        dinv[i] = rsqrtf((float)(v + 1));
        for (int z = v; z < pv; ++z) csr_ew[o + z] = 0u;   // zero padding slots
    }
    if (blockIdx.x == 0 && tid == 0) offsets[n] = cexcl[NCHUNKS];
}

// ------------------------------------------------------------------
// Packed CSR fill: 256 blocks aligned 1:1 with histo's edge slices.
// Stage the block's Hexcl u8 row (50 KB) into LDS; per edge, one
// packed LDS atomicAdd returns base+rank in one shot:
//   slot = offsets[c] + ((old >> sh) & 0xff)
// No rank buffer, no random H gather. base+count <= deg <= ~60, no
// byte carry. Entry order within a node segment is atomic-arrival
// order (fp32 sum-order tolerance, as every prior round).
// ------------------------------------------------------------------
__global__ __launch_bounds__(256) void fill_csr_kernel(const int* __restrict__ row,
                                                       const int* __restrict__ col,
                                                       const int* __restrict__ offsets,
                                                       const u8* __restrict__ H,
                                                       const float* __restrict__ dinv,
                                                       unsigned int* __restrict__ csr_ew) {
    extern __shared__ unsigned int hl[];       // HWORDS dwords = 50 KB
    int b = blockIdx.x;
    int tid = threadIdx.x;
    const unsigned int* Hrow = (const unsigned int*)(H + (size_t)b * N_NODES);
    for (int j = tid; j < HWORDS; j += 256) hl[j] = Hrow[j];
    __syncthreads();
    int e0 = b * EPB, e1 = e0 + EPB;
    for (int e = e0 + tid; e < e1; e += 256) {
        int c = col[e];
        int r = row[e];
        float w = dinv[c] * dinv[r];
        int sh = (c & 3) << 3;
        unsigned int old = atomicAdd(&hl[c >> 2], 1u << sh);
        int k = (int)((old >> sh) & 0xffu);
        csr_ew[offsets[c] + k] = (unsigned int)r | ((unsigned int)f2bf(w) << 16);
    }
}

// ------------------------------------------------------------------
// fp8 MFMA GEMM: C[N_PAD x 256] = A[N_PAD x K] @ Bt^T   (Bt is [256][K], fp8)
// 128x128 tile / block (4 waves 2x2), BK=128, async global_load_lds staging.
// ------------------------------------------------------------------
template <int K, bool RELU>
__global__ __launch_bounds__(256) void gemm_fp8(const u8* __restrict__ A,
                                                const u8* __restrict__ Bt,
                                                u8* __restrict__ C) {
    __shared__ u8 As[4 * 4096];
    __shared__ u8 Bs[4 * 4096];
    int tid = threadIdx.x;
    int lane = tid & 63;
    int w = tid >> 6;
    int wm = w & 1, wn = w >> 1;
    int l16 = lane & 15, quad = lane >> 4;
    int row0 = blockIdx.x * 128;
    int col0 = blockIdx.y * 128;
    f32x4 acc[4][4] = {};

    int sr = tid >> 1;             // staging row 0..127
    int sh = (tid & 1) * 16;       // half-plane-row byte offset
    const u8* ga = A + (size_t)(row0 + sr) * K + sh;
    const u8* gb = Bt + (size_t)(col0 + sr) * K + sh;

    #pragma unroll
    for (int k0 = 0; k0 < K; k0 += 128) {
        if (k0) __syncthreads();
        #pragma unroll
        for (int q = 0; q < 4; ++q) {   // k-plane within stage
            gl2lds16(ga + k0 + q * 32, As + q * 4096 + w * 1024);
            gl2lds16(gb + k0 + q * 32, Bs + q * 4096 + w * 1024);
        }
        __syncthreads();
        #pragma unroll
        for (int h = 0; h < 4; ++h) {
            long af[4], bfr[4];
            #pragma unroll
            for (int i = 0; i < 4; ++i)
                af[i] = *(const long*)&As[h * 4096 + (wm * 64 + i * 16 + l16) * 32 + quad * 8];
            #pragma unroll
            for (int j = 0; j < 4; ++j)
                bfr[j] = *(const long*)&Bs[h * 4096 + (wn * 64 + j * 16 + l16) * 32 + quad * 8];
            #pragma unroll
            for (int i = 0; i < 4; ++i)
                #pragma unroll
                for (int j = 0; j < 4; ++j)
                    acc[i][j] = __builtin_amdgcn_mfma_f32_16x16x32_fp8_fp8(af[i], bfr[j], acc[i][j], 0, 0, 0);
        }
    }
    // epilogue: C/D layout col=lane&15, row=quad*4+reg (dtype-independent)
    #pragma unroll
    for (int i = 0; i < 4; ++i) {
        int rowb = row0 + wm * 64 + i * 16 + quad * 4;
        #pragma unroll
        for (int r = 0; r < 4; ++r) {
            int grow = rowb + r;
            #pragma unroll
            for (int j = 0; j < 4; ++j) {
                int gcol = col0 + wn * 64 + j * 16 + l16;
                float v = acc[i][j][r];
                if (RELU) v = fmaxf(v, 0.f);
                C[(size_t)grow * H_F + gcol] = f32_fp8(v);
            }
        }
    }
}

// ------------------------------------------------------------------
// GCN aggregation, 128-ch fp8 (layer-0, pre-GEMM), NO relu.
// ------------------------------------------------------------------
__global__ __launch_bounds__(256) void aggregate128(const u8* __restrict__ hw,
                                                    const float* __restrict__ dinv,
                                                    const int* __restrict__ offsets,
                                                    const unsigned int* __restrict__ csr_ew,
                                                    u8* __restrict__ hout) {
    int w = threadIdx.x >> 6;
    int lane = threadIdx.x & 63;
    int i = blockIdx.x * 4 + w;
    if (i >= N_NODES) return;
    float di = dinv[i];
    const u8* base = hw + (size_t)lane * 2;
    unsigned int su = *(const unsigned short*)(base + (size_t)i * IN_F);
    f32x2 sv = fp8x2_f32_lo(su);
    float s = di * di;
    float a0 = s * sv.x, a1 = s * sv.y;
    int t = __builtin_amdgcn_readfirstlane(offsets[i]);
    int end = __builtin_amdgcn_readfirstlane(offsets[i + 1]);
    if (t < end) {
        uint4 eA = *(const uint4*)(csr_ew + t);
        uint4 eB = *(const uint4*)(csr_ew + t + 4);
        for (; t < end; t += 8) {
            uint4 nA, nB;
            if (t + 8 < end) {
                nA = *(const uint4*)(csr_ew + t + 8);
                nB = *(const uint4*)(csr_ew + t + 12);
            }
            unsigned int e[8] = {eA.x, eA.y, eA.z, eA.w, eB.x, eB.y, eB.z, eB.w};
            unsigned int v[8];
            #pragma unroll
            for (int u = 0; u < 8; ++u)
                v[u] = *(const unsigned short*)(base + (size_t)(e[u] & 0xffff) * IN_F);
            #pragma unroll
            for (int u = 0; u < 8; ++u) {
                float wq = bf2f((ushort)(e[u] >> 16));
                f32x2 f = fp8x2_f32_lo(v[u]);
                a0 += wq * f.x; a1 += wq * f.y;
            }
            eA = nA; eB = nB;
        }
    }
    unsigned int o = f32_fp8x2_lo(a0, a1, 0u);
    *(unsigned short*)(hout + (size_t)i * IN_F + lane * 2) = (unsigned short)(o & 0xffff);
}

// ------------------------------------------------------------------
// GCN aggregation, 256-ch fp8, + relu. Padded, pipelined, scalar descr.
// ------------------------------------------------------------------
__global__ __launch_bounds__(256) void aggregate256(const u8* __restrict__ hw,
                                                    const float* __restrict__ dinv,
                                                    const int* __restrict__ offsets,
                                                    const unsigned int* __restrict__ csr_ew,
                                                    u8* __restrict__ hout) {
    int w = threadIdx.x >> 6;
    int lane = threadIdx.x & 63;
    int i = blockIdx.x * 4 + w;
    if (i >= N_NODES) return;
    float di = dinv[i];
    const u8* base = hw + (size_t)lane * 4;
    unsigned int su = *(const unsigned int*)(base + (size_t)i * H_F);
    f32x2 slo = fp8x2_f32_lo(su), shi = fp8x2_f32_hi(su);
    float s = di * di;
    float a0 = s * slo.x, a1 = s * slo.y, a2 = s * shi.x, a3 = s * shi.y;
    int t = __builtin_amdgcn_readfirstlane(offsets[i]);
    int end = __builtin_amdgcn_readfirstlane(offsets[i + 1]);
    if (t < end) {
        uint4 eA = *(const uint4*)(csr_ew + t);
        uint4 eB = *(const uint4*)(csr_ew + t + 4);
        for (; t < end; t += 8) {
            uint4 nA, nB;
            if (t + 8 < end) {
                nA = *(const uint4*)(csr_ew + t + 8);
                nB = *(const uint4*)(csr_ew + t + 12);
            }
            unsigned int e[8] = {eA.x, eA.y, eA.z, eA.w, eB.x, eB.y, eB.z, eB.w};
            unsigned int v[8];
            #pragma unroll
            for (int u = 0; u < 8; ++u)
                v[u] = *(const unsigned int*)(base + (size_t)(e[u] & 0xffff) * H_F);
            #pragma unroll
            for (int u = 0; u < 8; ++u) {
                float wq = bf2f((ushort)(e[u] >> 16));
                f32x2 lo = fp8x2_f32_lo(v[u]), hi = fp8x2_f32_hi(v[u]);
                a0 += wq * lo.x; a1 += wq * lo.y;
                a2 += wq * hi.x; a3 += wq * hi.y;
            }
            eA = nA; eB = nB;
        }
    }
    unsigned int o = f32_fp8x2_lo(fmaxf(a0, 0.f), fmaxf(a1, 0.f), 0u);
    o = f32_fp8x2_hi(fmaxf(a2, 0.f), fmaxf(a3, 0.f), o);
    *(unsigned int*)(hout + (size_t)i * H_F + lane * 4) = o;
}

// ------------------------------------------------------------------
// Fused pool + MLP head: one 1024-thread block (16 waves) per graph.
// ------------------------------------------------------------------
__global__ __launch_bounds__(1024) void pool_mlp_kernel(const u8* __restrict__ h,
                                                        const int* __restrict__ gstart,
                                                        const float* __restrict__ Wm1,
                                                        const float* __restrict__ bm1,
                                                        const float* __restrict__ Wm2,
                                                        const float* __restrict__ bm2,
                                                        float* __restrict__ out) {
    __shared__ float sm[16][H_F];
    __shared__ float p[H_F];
    __shared__ float hmid[H_F];
    __shared__ float lastv[OUT_F];
    __shared__ float stats[2];
    int g = blockIdx.x;
    int s = gstart[g], e = gstart[g + 1];
    int w = threadIdx.x >> 6;        // 0..15
    int lane = threadIdx.x & 63;
    float a0 = 0.f, a1 = 0.f, a2 = 0.f, a3 = 0.f;
    for (int i = s + w; i < e; i += 16) {
        unsigned int v = *(const unsigned int*)(h + (size_t)i * H_F + lane * 4);
        f32x2 lo = fp8x2_f32_lo(v), hi = fp8x2_f32_hi(v);
        a0 += lo.x; a1 += lo.y; a2 += hi.x; a3 += hi.y;
    }
    *(f32x4*)&sm[w][lane * 4] = (f32x4){a0, a1, a2, a3};
    __syncthreads();
    int j = threadIdx.x;
    int cnt = e - s;
    if (j < H_F) {
        float t = 0.f;
        #pragma unroll
        for (int k = 0; k < 16; ++k) t += sm[k][j];
        p[j] = t / (float)max(cnt, 1);
    }
    __syncthreads();
    if (j < H_F) {
        float acc = bm1[j];
        for (int k = 0; k < H_F; ++k) acc += p[k] * Wm1[k * H_F + j];
        hmid[j] = fmaxf(acc, 0.f);
    }
    __syncthreads();
    if (j < OUT_F) {
        float a = bm2[j];
        for (int k = 0; k < H_F; ++k) a += hmid[k] * Wm2[k * OUT_F + j];
        lastv[j] = a;
    }
    __syncthreads();
    if (j == 0) {
        float m = -1e30f;
        for (int o = 0; o < OUT_F; ++o) m = fmaxf(m, lastv[o]);
        float sxp = 0.f;
        for (int o = 0; o < OUT_F; ++o) sxp += expf(lastv[o] - m);
        stats[0] = m; stats[1] = logf(sxp);
    }
    __syncthreads();
    if (j < OUT_F) {
        float v = lastv[j];
        out[g * OUT_F + j] = v - stats[0] - stats[1];
        out[(size_t)N_G * OUT_F + g * OUT_F + j] = 1.f / (1.f + expf(-v));
        out[(size_t)2 * N_G * OUT_F + g * OUT_F + j] = v;
    }
}

// ------------------------------------------------------------------
extern "C" void kernel_launch(void* const* d_in, const int* in_sizes, int n_in,
                              void* d_out, int out_size, void* d_ws, size_t ws_size,
                              hipStream_t stream) {
    const float* x   = (const float*)d_in[0];
    const int* edge_index = (const int*)d_in[1];
    const int* batch = (const int*)d_in[3];
    const float* W0  = (const float*)d_in[4];
    const float* W1  = (const float*)d_in[5];
    const float* W2  = (const float*)d_in[6];
    const float* Wm1 = (const float*)d_in[7];
    const float* bm1 = (const float*)d_in[8];
    const float* Wm2 = (const float*)d_in[9];
    const float* bm2 = (const float*)d_in[10];
    float* out = (float*)d_out;

    char* ws = (char*)d_ws;
    size_t off = 0;
    auto alloc = [&](size_t bytes) -> void* {
        void* p = ws + off; off += (bytes + 255) & ~(size_t)255; return p;
    };
    u8* xb       = (u8*)alloc((size_t)N_PAD * IN_F);
    u8* bufA     = (u8*)alloc((size_t)N_PAD * H_F);
    u8* bufB     = (u8*)alloc((size_t)N_PAD * H_F);
    u8* t0       = (u8*)alloc((size_t)N_PAD * IN_F);
    u8* W0t      = (u8*)alloc((size_t)H_F * IN_F);
    u8* W1t      = (u8*)alloc((size_t)H_F * H_F);
    u8* W2t      = (u8*)alloc((size_t)H_F * H_F);
    float* dinv    = (float*)alloc((size_t)N_NODES * 4);
    int*   counts  = (int*)alloc((size_t)N_NODES * 4);
    int*   offsets = (int*)alloc((size_t)(N_NODES + 1) * 4);
    u8*    H       = (u8*)alloc((size_t)HB * N_NODES);
    unsigned int* csr_ew = (unsigned int*)alloc((size_t)CSR_CAP * 4);
    int*   csum    = (int*)alloc((size_t)256 * 4);
    int*   gstart  = (int*)alloc((size_t)(N_G + 1) * 4);

    const int* row = edge_index;
    const int* col = edge_index + N_EDGES;

    histo_kernel<<<HB, 256, HWORDS * 4, stream>>>(col, H);
    convert_chunk_kernel<<<CC_GS, 256, 0, stream>>>(H, counts, csum, x, xb,
                                                    W0, W0t, W1, W1t, W2, W2t,
                                                    batch, gstart);
    scan_dinv_kernel<<<NCHUNKS, 256, 0, stream>>>(counts, csum, offsets, dinv,
                                                  csr_ew, N_NODES);
    fill_csr_kernel<<<HB, 256, HWORDS * 4, stream>>>(row, col, offsets, H,
                                                     dinv, csr_ew);

    dim3 gg(N_PAD / 128, H_F / 128);
    int agg_blocks = (N_NODES + 3) / 4;
    // layer 0: aggregate-first (linear ops commute), relu in GEMM epilogue
    aggregate128<<<agg_blocks, 256, 0, stream>>>(xb, dinv, offsets, csr_ew, t0);
    gemm_fp8<IN_F, true><<<gg, 256, 0, stream>>>(t0, W0t, bufA);
    // layer 1
    gemm_fp8<H_F, false><<<gg, 256, 0, stream>>>(bufA, W1t, bufB);
    aggregate256<<<agg_blocks, 256, 0, stream>>>(bufB, dinv, offsets, csr_ew, bufA);
    // layer 2
    gemm_fp8<H_F, false><<<gg, 256, 0, stream>>>(bufA, W2t, bufB);
    aggregate256<<<agg_blocks, 256, 0, stream>>>(bufB, dinv, offsets, csr_ew, bufA);

    pool_mlp_kernel<<<N_G, 1024, 0, stream>>>(bufA, gstart, Wm1, bm1, Wm2, bm2, out);
}

// Round 12
// 267.574 us; speedup vs baseline: 1.1793x; 1.0038x over previous
//
#include <hip/hip_runtime.h>
#include <math.h>

#define N_NODES 50000
#define N_PAD   50048          // padded to multiple of 128 for GEMM tiles
#define N_EDGES 800000
#define CSR_CAP 1200000        // >= sum pad8(deg) <= 800000 + 50000*7
#define IN_F 128
#define H_F 256
#define OUT_F 10
#define N_G 128
#define NCHUNKS 196            // ceil(N_NODES/256)

// LDS-histogram geometry: 256 blocks, each owns a contiguous edge slice
#define HB 256                 // histo blocks
#define EPB (N_EDGES / HB)     // 3125 edges per block (exact)
#define HWORDS (N_NODES / 4)   // 12500 packed dwords = 50 KB (u8 counters)

typedef __attribute__((ext_vector_type(4))) float f32x4;
typedef __attribute__((ext_vector_type(2))) float f32x2;
typedef unsigned char u8;

// ---- fp8 e4m3 (OCP) helpers: HW packed converts (imm word-select) ----
__device__ inline f32x2 fp8x2_f32_lo(unsigned int v) {
    return __builtin_amdgcn_cvt_pk_f32_fp8(v, false);
}
__device__ inline f32x2 fp8x2_f32_hi(unsigned int v) {
    return __builtin_amdgcn_cvt_pk_f32_fp8(v, true);
}
__device__ inline unsigned int f32_fp8x2_lo(float a, float b, unsigned int old) {
    return __builtin_amdgcn_cvt_pk_fp8_f32(a, b, old, false);
}
__device__ inline unsigned int f32_fp8x2_hi(float a, float b, unsigned int old) {
    return __builtin_amdgcn_cvt_pk_fp8_f32(a, b, old, true);
}
__device__ inline u8 f32_fp8(float a) {
    return (u8)(f32_fp8x2_lo(a, a, 0u) & 0xff);
}
// ---- bf16 helpers (packed CSR weight) ----
__device__ inline ushort f2bf(float x) {
    union { float f; unsigned int u; } v; v.f = x;
    unsigned int r = v.u + 0x7fff + ((v.u >> 16) & 1);
    return (ushort)(r >> 16);
}
__device__ inline float bf2f(ushort u) {
    union { unsigned int u; float f; } v; v.u = ((unsigned int)u) << 16; return v.f;
}

// async global->LDS, 16 B per lane; lds dest = wave-uniform base + lane*16
__device__ inline void gl2lds16(const void* g, void* l) {
    __builtin_amdgcn_global_load_lds(
        (const __attribute__((address_space(1))) unsigned int*)g,
        (__attribute__((address_space(3))) unsigned int*)l,
        16, 0, 0);
}

// ------------------------------------------------------------------
// LDS histogram: 256 blocks, each counts its 3125-edge slice over the
// FULL node range in u8-packed LDS counters (50 KB dynamic). NO global
// atomics. 2-wide unrolled edge loop (independent LDS atomics) keeps
// twice the loads in flight. Max cell count ~6, no byte carry.
// ------------------------------------------------------------------
__global__ __launch_bounds__(256) void histo_kernel(const int* __restrict__ col,
                                                    u8* __restrict__ H) {
    extern __shared__ unsigned int hcnt[];     // HWORDS dwords = 50 KB
    int b = blockIdx.x;
    int tid = threadIdx.x;
    for (int j = tid; j < HWORDS; j += 256) hcnt[j] = 0u;
    __syncthreads();
    int e0 = b * EPB, e1 = e0 + EPB;
    for (int e = e0 + tid; e < e1; e += 512) {
        int c0 = col[e];
        int c1 = (e + 256 < e1) ? col[e + 256] : -1;
        atomicAdd(&hcnt[c0 >> 2], 1u << ((c0 & 3) << 3));
        if (c1 >= 0) atomicAdd(&hcnt[c1 >> 2], 1u << ((c1 & 3) << 3));
    }
    __syncthreads();
    unsigned int* Hrow = (unsigned int*)(H + (size_t)b * N_NODES);
    for (int j = tid; j < HWORDS; j += 256) Hrow[j] = hcnt[j];
}

// ------------------------------------------------------------------
// Fused: chunk-prefix (blocks 0..195) + fp8 converts + graph starts.
// chunk role: per node i, turn H[b][i] (u8) into the EXCLUSIVE prefix
// over b (in place, 16-wide unroll: 16 strided loads in flight halves
// the dependent-group count vs 8-wide), emit counts[i] and csum.
// ------------------------------------------------------------------
#define CC_CHUNK 196
#define CC_X    (CC_CHUNK + 6250)
#define CC_T0   (CC_X + 128)
#define CC_T1   (CC_T0 + 256)
#define CC_T2   (CC_T1 + 256)
#define CC_GS   (CC_T2 + NCHUNKS)

__global__ __launch_bounds__(256) void convert_chunk_kernel(
    u8* __restrict__ H, int* __restrict__ counts, int* __restrict__ csum,
    const float* __restrict__ x, u8* __restrict__ xb,
    const float* __restrict__ W0, u8* __restrict__ W0t,
    const float* __restrict__ W1, u8* __restrict__ W1t,
    const float* __restrict__ W2, u8* __restrict__ W2t,
    const int* __restrict__ batch, int* __restrict__ gstart) {
    int b = blockIdx.x;
    int tid = threadIdx.x;
    if (b < CC_CHUNK) {
        int i = b * 256 + tid;
        int total = 0;
        if (i < N_NODES) {
            u8* ci = H + i;
            int s = 0;
            for (int b0 = 0; b0 < HB; b0 += 16) {
                int h[16];
                #pragma unroll
                for (int u = 0; u < 16; ++u)
                    h[u] = ci[(size_t)(b0 + u) * N_NODES];
                #pragma unroll
                for (int u = 0; u < 16; ++u) {
                    ci[(size_t)(b0 + u) * N_NODES] = (u8)s;
                    s += h[u];
                }
            }
            total = s;
            counts[i] = total;
        }
        int v = (i < N_NODES) ? ((total + 7) & ~7) : 0;
        #pragma unroll
        for (int off = 32; off; off >>= 1) v += __shfl_down(v, off);
        __shared__ int ws[4];
        if ((tid & 63) == 0) ws[tid >> 6] = v;
        __syncthreads();
        if (tid == 0) csum[b] = ws[0] + ws[1] + ws[2] + ws[3];
    } else if (b < CC_X) {
        int i = (b - CC_CHUNK) * 256 + tid;     // < 1,600,000 exactly
        float4 v = *(const float4*)(x + (size_t)i * 4);
        unsigned int p = f32_fp8x2_lo(v.x, v.y, 0u);
        p = f32_fp8x2_hi(v.z, v.w, p);
        *(unsigned int*)(xb + (size_t)i * 4) = p;
    } else if (b < CC_T0) {
        int idx = (b - CC_X) * 256 + tid;       // < 32768
        int k = idx >> 8, nn = idx & 255;       // K=128, Nc=256
        W0t[nn * IN_F + k] = f32_fp8(W0[idx]);
    } else if (b < CC_T1) {
        int idx = (b - CC_T0) * 256 + tid;      // < 65536
        int k = idx >> 8, nn = idx & 255;
        W1t[nn * H_F + k] = f32_fp8(W1[idx]);
    } else if (b < CC_T2) {
        int idx = (b - CC_T1) * 256 + tid;
        int k = idx >> 8, nn = idx & 255;
        W2t[nn * H_F + k] = f32_fp8(W2[idx]);
    } else {
        int i = (b - CC_T2) * 256 + tid;
        if (i >= N_NODES) return;
        int bb = batch[i];
        if (i == 0) {
            for (int g = 0; g <= bb; ++g) gstart[g] = 0;
        } else {
            int p = batch[i - 1];
            if (p != bb) { for (int g = p + 1; g <= bb; ++g) gstart[g] = i; }
        }
        if (i == N_NODES - 1) {
            for (int g = bb + 1; g <= N_G; ++g) gstart[g] = N_NODES;
        }
    }
}

// ------------------------------------------------------------------
// scan (over padded counts, csum-based block base) + dinv + zero
// padding CSR slots. (Verified R6 form.)
// ------------------------------------------------------------------
__global__ __launch_bounds__(256) void scan_dinv_kernel(const int* __restrict__ counts,
                                                        const int* __restrict__ csum,
                                                        int* __restrict__ offsets,
                                                        float* __restrict__ dinv,
                                                        unsigned int* __restrict__ csr_ew,
                                                        int n) {
    int tid = threadIdx.x;
    int lane = tid & 63, wid = tid >> 6;
    int cv = (tid < NCHUNKS) ? csum[tid] : 0;
    int xc = cv;
    #pragma unroll
    for (int off = 1; off < 64; off <<= 1) {
        int t = __shfl_up(xc, off);
        if (lane >= off) xc += t;
    }
    __shared__ int cw[4], cpre[4];
    __shared__ int cexcl[257];
    if (lane == 63) cw[wid] = xc;
    __syncthreads();
    if (tid == 0) { int s = 0; for (int k = 0; k < 4; ++k) { cpre[k] = s; s += cw[k]; } }
    __syncthreads();
    cexcl[tid] = cpre[wid] + xc - cv;
    if (tid == 255) cexcl[256] = cpre[3] + cw[3];
    __syncthreads();
    int base = cexcl[blockIdx.x];
    int i = blockIdx.x * 256 + tid;
    int v = (i < n) ? counts[i] : 0;
    int pv = (v + 7) & ~7;
    int x = pv;
    #pragma unroll
    for (int off = 1; off < 64; off <<= 1) {
        int t = __shfl_up(x, off);
        if (lane >= off) x += t;
    }
    __shared__ int wsum[4], wpre[4];
    if (lane == 63) wsum[wid] = x;
    __syncthreads();
    if (tid == 0) { int s = 0; for (int k = 0; k < 4; ++k) { wpre[k] = s; s += wsum[k]; } }
    __syncthreads();
    if (i < n) {
        int o = base + wpre[wid] + x - pv;       // exclusive, padded
        offsets[i] = o;
        dinv[i] = rsqrtf((float)(v + 1));
        for (int z = v; z < pv; ++z) csr_ew[o + z] = 0u;   // zero padding slots
    }
    if (blockIdx.x == 0 && tid == 0) offsets[n] = cexcl[NCHUNKS];
}

// ------------------------------------------------------------------
// Packed CSR fill: 256 blocks aligned 1:1 with histo's edge slices.
// Stage the block's Hexcl u8 row (50 KB) into LDS; per edge, one
// packed LDS atomicAdd returns base+rank in one shot. 2-wide unrolled
// edge loop (independent iterations) for ILP.
// ------------------------------------------------------------------
__global__ __launch_bounds__(256) void fill_csr_kernel(const int* __restrict__ row,
                                                       const int* __restrict__ col,
                                                       const int* __restrict__ offsets,
                                                       const u8* __restrict__ H,
                                                       const float* __restrict__ dinv,
                                                       unsigned int* __restrict__ csr_ew) {
    extern __shared__ unsigned int hl[];       // HWORDS dwords = 50 KB
    int b = blockIdx.x;
    int tid = threadIdx.x;
    const unsigned int* Hrow = (const unsigned int*)(H + (size_t)b * N_NODES);
    for (int j = tid; j < HWORDS; j += 256) hl[j] = Hrow[j];
    __syncthreads();
    int e0 = b * EPB, e1 = e0 + EPB;
    for (int e = e0 + tid; e < e1; e += 512) {
        int eb = e + 256;
        int c0 = col[e];
        int r0 = row[e];
        int c1 = -1, r1 = 0;
        if (eb < e1) { c1 = col[eb]; r1 = row[eb]; }
        float w0 = dinv[c0] * dinv[r0];
        float w1 = (c1 >= 0) ? dinv[c1] * dinv[r1] : 0.f;
        int sh0 = (c0 & 3) << 3;
        unsigned int old0 = atomicAdd(&hl[c0 >> 2], 1u << sh0);
        int k0 = (int)((old0 >> sh0) & 0xffu);
        csr_ew[offsets[c0] + k0] = (unsigned int)r0 | ((unsigned int)f2bf(w0) << 16);
        if (c1 >= 0) {
            int sh1 = (c1 & 3) << 3;
            unsigned int old1 = atomicAdd(&hl[c1 >> 2], 1u << sh1);
            int k1 = (int)((old1 >> sh1) & 0xffu);
            csr_ew[offsets[c1] + k1] = (unsigned int)r1 | ((unsigned int)f2bf(w1) << 16);
        }
    }
}

// ------------------------------------------------------------------
// fp8 MFMA GEMM: C[N_PAD x 256] = A[N_PAD x K] @ Bt^T   (Bt is [256][K], fp8)
// 128x128 tile / block (4 waves 2x2), BK=128, async global_load_lds staging.
// ------------------------------------------------------------------
template <int K, bool RELU>
__global__ __launch_bounds__(256) void gemm_fp8(const u8* __restrict__ A,
                                                const u8* __restrict__ Bt,
                                                u8* __restrict__ C) {
    __shared__ u8 As[4 * 4096];
    __shared__ u8 Bs[4 * 4096];
    int tid = threadIdx.x;
    int lane = tid & 63;
    int w = tid >> 6;
    int wm = w & 1, wn = w >> 1;
    int l16 = lane & 15, quad = lane >> 4;
    int row0 = blockIdx.x * 128;
    int col0 = blockIdx.y * 128;
    f32x4 acc[4][4] = {};

    int sr = tid >> 1;             // staging row 0..127
    int sh = (tid & 1) * 16;       // half-plane-row byte offset
    const u8* ga = A + (size_t)(row0 + sr) * K + sh;
    const u8* gb = Bt + (size_t)(col0 + sr) * K + sh;

    #pragma unroll
    for (int k0 = 0; k0 < K; k0 += 128) {
        if (k0) __syncthreads();
        #pragma unroll
        for (int q = 0; q < 4; ++q) {   // k-plane within stage
            gl2lds16(ga + k0 + q * 32, As + q * 4096 + w * 1024);
            gl2lds16(gb + k0 + q * 32, Bs + q * 4096 + w * 1024);
        }
        __syncthreads();
        #pragma unroll
        for (int h = 0; h < 4; ++h) {
            long af[4], bfr[4];
            #pragma unroll
            for (int i = 0; i < 4; ++i)
                af[i] = *(const long*)&As[h * 4096 + (wm * 64 + i * 16 + l16) * 32 + quad * 8];
            #pragma unroll
            for (int j = 0; j < 4; ++j)
                bfr[j] = *(const long*)&Bs[h * 4096 + (wn * 64 + j * 16 + l16) * 32 + quad * 8];
            #pragma unroll
            for (int i = 0; i < 4; ++i)
                #pragma unroll
                for (int j = 0; j < 4; ++j)
                    acc[i][j] = __builtin_amdgcn_mfma_f32_16x16x32_fp8_fp8(af[i], bfr[j], acc[i][j], 0, 0, 0);
        }
    }
    // epilogue: C/D layout col=lane&15, row=quad*4+reg (dtype-independent)
    #pragma unroll
    for (int i = 0; i < 4; ++i) {
        int rowb = row0 + wm * 64 + i * 16 + quad * 4;
        #pragma unroll
        for (int r = 0; r < 4; ++r) {
            int grow = rowb + r;
            #pragma unroll
            for (int j = 0; j < 4; ++j) {
                int gcol = col0 + wn * 64 + j * 16 + l16;
                float v = acc[i][j][r];
                if (RELU) v = fmaxf(v, 0.f);
                C[(size_t)grow * H_F + gcol] = f32_fp8(v);
            }
        }
    }
}

// ------------------------------------------------------------------
// GCN aggregation, 128-ch fp8 (layer-0, pre-GEMM), NO relu.
// ------------------------------------------------------------------
__global__ __launch_bounds__(256) void aggregate128(const u8* __restrict__ hw,
                                                    const float* __restrict__ dinv,
                                                    const int* __restrict__ offsets,
                                                    const unsigned int* __restrict__ csr_ew,
                                                    u8* __restrict__ hout) {
    int w = threadIdx.x >> 6;
    int lane = threadIdx.x & 63;
    int i = blockIdx.x * 4 + w;
    if (i >= N_NODES) return;
    float di = dinv[i];
    const u8* base = hw + (size_t)lane * 2;
    unsigned int su = *(const unsigned short*)(base + (size_t)i * IN_F);
    f32x2 sv = fp8x2_f32_lo(su);
    float s = di * di;
    float a0 = s * sv.x, a1 = s * sv.y;
    int t = __builtin_amdgcn_readfirstlane(offsets[i]);
    int end = __builtin_amdgcn_readfirstlane(offsets[i + 1]);
    if (t < end) {
        uint4 eA = *(const uint4*)(csr_ew + t);
        uint4 eB = *(const uint4*)(csr_ew + t + 4);
        for (; t < end; t += 8) {
            uint4 nA, nB;
            if (t + 8 < end) {
                nA = *(const uint4*)(csr_ew + t + 8);
                nB = *(const uint4*)(csr_ew + t + 12);
            }
            unsigned int e[8] = {eA.x, eA.y, eA.z, eA.w, eB.x, eB.y, eB.z, eB.w};
            unsigned int v[8];
            #pragma unroll
            for (int u = 0; u < 8; ++u)
                v[u] = *(const unsigned short*)(base + (size_t)(e[u] & 0xffff) * IN_F);
            #pragma unroll
            for (int u = 0; u < 8; ++u) {
                float wq = bf2f((ushort)(e[u] >> 16));
                f32x2 f = fp8x2_f32_lo(v[u]);
                a0 += wq * f.x; a1 += wq * f.y;
            }
            eA = nA; eB = nB;
        }
    }
    unsigned int o = f32_fp8x2_lo(a0, a1, 0u);
    *(unsigned short*)(hout + (size_t)i * IN_F + lane * 2) = (unsigned short)(o & 0xffff);
}

// ------------------------------------------------------------------
// GCN aggregation, 256-ch fp8, + relu. Padded, pipelined, scalar descr.
// ------------------------------------------------------------------
__global__ __launch_bounds__(256) void aggregate256(const u8* __restrict__ hw,
                                                    const float* __restrict__ dinv,
                                                    const int* __restrict__ offsets,
                                                    const unsigned int* __restrict__ csr_ew,
                                                    u8* __restrict__ hout) {
    int w = threadIdx.x >> 6;
    int lane = threadIdx.x & 63;
    int i = blockIdx.x * 4 + w;
    if (i >= N_NODES) return;
    float di = dinv[i];
    const u8* base = hw + (size_t)lane * 4;
    unsigned int su = *(const unsigned int*)(base + (size_t)i * H_F);
    f32x2 slo = fp8x2_f32_lo(su), shi = fp8x2_f32_hi(su);
    float s = di * di;
    float a0 = s * slo.x, a1 = s * slo.y, a2 = s * shi.x, a3 = s * shi.y;
    int t = __builtin_amdgcn_readfirstlane(offsets[i]);
    int end = __builtin_amdgcn_readfirstlane(offsets[i + 1]);
    if (t < end) {
        uint4 eA = *(const uint4*)(csr_ew + t);
        uint4 eB = *(const uint4*)(csr_ew + t + 4);
        for (; t < end; t += 8) {
            uint4 nA, nB;
            if (t + 8 < end) {
                nA = *(const uint4*)(csr_ew + t + 8);
                nB = *(const uint4*)(csr_ew + t + 12);
            }
            unsigned int e[8] = {eA.x, eA.y, eA.z, eA.w, eB.x, eB.y, eB.z, eB.w};
            unsigned int v[8];
            #pragma unroll
            for (int u = 0; u < 8; ++u)
                v[u] = *(const unsigned int*)(base + (size_t)(e[u] & 0xffff) * H_F);
            #pragma unroll
            for (int u = 0; u < 8; ++u) {
                float wq = bf2f((ushort)(e[u] >> 16));
                f32x2 lo = fp8x2_f32_lo(v[u]), hi = fp8x2_f32_hi(v[u]);
                a0 += wq * lo.x; a1 += wq * lo.y;
                a2 += wq * hi.x; a3 += wq * hi.y;
            }
            eA = nA; eB = nB;
        }
    }
    unsigned int o = f32_fp8x2_lo(fmaxf(a0, 0.f), fmaxf(a1, 0.f), 0u);
    o = f32_fp8x2_hi(fmaxf(a2, 0.f), fmaxf(a3, 0.f), o);
    *(unsigned int*)(hout + (size_t)i * H_F + lane * 4) = o;
}

// ------------------------------------------------------------------
// Fused pool + MLP head: one 1024-thread block (16 waves) per graph.
// ------------------------------------------------------------------
__global__ __launch_bounds__(1024) void pool_mlp_kernel(const u8* __restrict__ h,
                                                        const int* __restrict__ gstart,
                                                        const float* __restrict__ Wm1,
                                                        const float* __restrict__ bm1,
                                                        const float* __restrict__ Wm2,
                                                        const float* __restrict__ bm2,
                                                        float* __restrict__ out) {
    __shared__ float sm[16][H_F];
    __shared__ float p[H_F];
    __shared__ float hmid[H_F];
    __shared__ float lastv[OUT_F];
    __shared__ float stats[2];
    int g = blockIdx.x;
    int s = gstart[g], e = gstart[g + 1];
    int w = threadIdx.x >> 6;        // 0..15
    int lane = threadIdx.x & 63;
    float a0 = 0.f, a1 = 0.f, a2 = 0.f, a3 = 0.f;
    for (int i = s + w; i < e; i += 16) {
        unsigned int v = *(const unsigned int*)(h + (size_t)i * H_F + lane * 4);
        f32x2 lo = fp8x2_f32_lo(v), hi = fp8x2_f32_hi(v);
        a0 += lo.x; a1 += lo.y; a2 += hi.x; a3 += hi.y;
    }
    *(f32x4*)&sm[w][lane * 4] = (f32x4){a0, a1, a2, a3};
    __syncthreads();
    int j = threadIdx.x;
    int cnt = e - s;
    if (j < H_F) {
        float t = 0.f;
        #pragma unroll
        for (int k = 0; k < 16; ++k) t += sm[k][j];
        p[j] = t / (float)max(cnt, 1);
    }
    __syncthreads();
    if (j < H_F) {
        float acc = bm1[j];
        for (int k = 0; k < H_F; ++k) acc += p[k] * Wm1[k * H_F + j];
        hmid[j] = fmaxf(acc, 0.f);
    }
    __syncthreads();
    if (j < OUT_F) {
        float a = bm2[j];
        for (int k = 0; k < H_F; ++k) a += hmid[k] * Wm2[k * OUT_F + j];
        lastv[j] = a;
    }
    __syncthreads();
    if (j == 0) {
        float m = -1e30f;
        for (int o = 0; o < OUT_F; ++o) m = fmaxf(m, lastv[o]);
        float sxp = 0.f;
        for (int o = 0; o < OUT_F; ++o) sxp += expf(lastv[o] - m);
        stats[0] = m; stats[1] = logf(sxp);
    }
    __syncthreads();
    if (j < OUT_F) {
        float v = lastv[j];
        out[g * OUT_F + j] = v - stats[0] - stats[1];
        out[(size_t)N_G * OUT_F + g * OUT_F + j] = 1.f / (1.f + expf(-v));
        out[(size_t)2 * N_G * OUT_F + g * OUT_F + j] = v;
    }
}

// ------------------------------------------------------------------
extern "C" void kernel_launch(void* const* d_in, const int* in_sizes, int n_in,
                              void* d_out, int out_size, void* d_ws, size_t ws_size,
                              hipStream_t stream) {
    const float* x   = (const float*)d_in[0];
    const int* edge_index = (const int*)d_in[1];
    const int* batch = (const int*)d_in[3];
    const float* W0  = (const float*)d_in[4];
    const float* W1  = (const float*)d_in[5];
    const float* W2  = (const float*)d_in[6];
    const float* Wm1 = (const float*)d_in[7];
    const float* bm1 = (const float*)d_in[8];
    const float* Wm2 = (const float*)d_in[9];
    const float* bm2 = (const float*)d_in[10];
    float* out = (float*)d_out;

    char* ws = (char*)d_ws;
    size_t off = 0;
    auto alloc = [&](size_t bytes) -> void* {
        void* p = ws + off; off += (bytes + 255) & ~(size_t)255; return p;
    };
    u8* xb       = (u8*)alloc((size_t)N_PAD * IN_F);
    u8* bufA     = (u8*)alloc((size_t)N_PAD * H_F);
    u8* bufB     = (u8*)alloc((size_t)N_PAD * H_F);
    u8* t0       = (u8*)alloc((size_t)N_PAD * IN_F);
    u8* W0t      = (u8*)alloc((size_t)H_F * IN_F);
    u8* W1t      = (u8*)alloc((size_t)H_F * H_F);
    u8* W2t      = (u8*)alloc((size_t)H_F * H_F);
    float* dinv    = (float*)alloc((size_t)N_NODES * 4);
    int*   counts  = (int*)alloc((size_t)N_NODES * 4);
    int*   offsets = (int*)alloc((size_t)(N_NODES + 1) * 4);
    u8*    H       = (u8*)alloc((size_t)HB * N_NODES);
    unsigned int* csr_ew = (unsigned int*)alloc((size_t)CSR_CAP * 4);
    int*   csum    = (int*)alloc((size_t)256 * 4);
    int*   gstart  = (int*)alloc((size_t)(N_G + 1) * 4);

    const int* row = edge_index;
    const int* col = edge_index + N_EDGES;

    histo_kernel<<<HB, 256, HWORDS * 4, stream>>>(col, H);
    convert_chunk_kernel<<<CC_GS, 256, 0, stream>>>(H, counts, csum, x, xb,
                                                    W0, W0t, W1, W1t, W2, W2t,
                                                    batch, gstart);
    scan_dinv_kernel<<<NCHUNKS, 256, 0, stream>>>(counts, csum, offsets, dinv,
                                                  csr_ew, N_NODES);
    fill_csr_kernel<<<HB, 256, HWORDS * 4, stream>>>(row, col, offsets, H,
                                                     dinv, csr_ew);

    dim3 gg(N_PAD / 128, H_F / 128);
    int agg_blocks = (N_NODES + 3) / 4;
    // layer 0: aggregate-first (linear ops commute), relu in GEMM epilogue
    aggregate128<<<agg_blocks, 256, 0, stream>>>(xb, dinv, offsets, csr_ew, t0);
    gemm_fp8<IN_F, true><<<gg, 256, 0, stream>>>(t0, W0t, bufA);
    // layer 1
    gemm_fp8<H_F, false><<<gg, 256, 0, stream>>>(bufA, W1t, bufB);
    aggregate256<<<agg_blocks, 256, 0, stream>>>(bufB, dinv, offsets, csr_ew, bufA);
    // layer 2
    gemm_fp8<H_F, false><<<gg, 256, 0, stream>>>(bufA, W2t, bufB);
    aggregate256<<<agg_blocks, 256, 0, stream>>>(bufB, dinv, offsets, csr_ew, bufA);

    pool_mlp_kernel<<<N_G, 1024, 0, stream>>>(bufA, gstart, Wm1, bm1, Wm2, bm2, out);
}